// Round 11
// baseline (483.115 us; speedup 1.0000x reference)
//
#include <hip/hip_runtime.h>

// ---------------------------------------------------------------------------
// RVMixtureSynthesizers: q = query@Wq^T + bq ; k = key@Wk^T + bk
//   energy = q@k^T + attn_bias ; attention = softmax(energy) ; out = attention@value
// Outputs: out [16,1024,1024] fp32, attention [16,1024,1024] fp32 (concat in d_out)
//
// R10: R9's algebra (energy = Q·(Wq^T Wk)·K^T + v1 + v2 + c) with R5's exact
// memory topology restored: q splits in d_out.out (R5-proj pattern), all other
// buffers in ws, launch order isomorphic to R5. Pure layout/order change vs R9.
// ---------------------------------------------------------------------------

#define AS1 __attribute__((address_space(1)))
#define AS3 __attribute__((address_space(3)))
#define VMCNT(n) asm volatile("s_waitcnt vmcnt(" #n ")" ::: "memory")
#define LGKM(n)  asm volatile("s_waitcnt lgkmcnt(" #n ")" ::: "memory")
#define SBARRIER asm volatile("s_barrier" ::: "memory")
#define SB0 __builtin_amdgcn_sched_barrier(0)

typedef __bf16 bf16;
typedef __bf16 bf16x4 __attribute__((ext_vector_type(4)));
typedef __bf16 bf16x8 __attribute__((ext_vector_type(8)));
typedef float  f32x4  __attribute__((ext_vector_type(4)));
typedef float  f32x16 __attribute__((ext_vector_type(16)));

constexpr int BATCH = 16;
constexpr int S = 1024;
constexpr int D = 1024;
constexpr long NBSD = (long)BATCH * S * D;   // 16777216

constexpr int GBM = 256, GBN = 256, GBK = 32;
constexpr int NTK = 1024 / GBK;              // 32 K-tiles
constexpr int ARR = GBM * GBK;               // 8192 elems = 16 KB per array

__device__ __forceinline__ void stage16(const bf16* src, const bf16* dst) {
  __builtin_amdgcn_global_load_lds((const AS1 void*)src, (AS3 void*)dst, 16, 0, 0);
}

// ---------------------------------------------------------------------------
// fp32 -> (hi,lo) bf16 split + fused dot with w (v[row] = row . w).
// One wave per row of 1024; grid 4096 x 256 (4 waves/block).
__global__ __launch_bounds__(256) void split_convert_dot(
    const float* __restrict__ in, bf16* __restrict__ hi, bf16* __restrict__ lo,
    const float* __restrict__ w, float* __restrict__ v) {
  const int wid = threadIdx.x >> 6, lane = threadIdx.x & 63;
  const long row = (long)blockIdx.x * 4 + wid;
  const f32x4* src = (const f32x4*)(in + row * 1024);
  const f32x4* w4 = (const f32x4*)w;
  float acc = 0.f;
#pragma unroll
  for (int it = 0; it < 4; ++it) {
    const int idx = it * 64 + lane;
    f32x4 x = src[idx];
    f32x4 wv = w4[idx];
    bf16x4 h, l;
#pragma unroll
    for (int j = 0; j < 4; ++j) {
      float vv = x[j];
      bf16 hh = (bf16)vv;
      h[j] = hh;
      l[j] = (bf16)(vv - (float)hh);
      acc += vv * wv[j];
    }
    *(bf16x4*)(hi + row * 1024 + idx * 4) = h;
    *(bf16x4*)(lo + row * 1024 + idx * 4) = l;
  }
#pragma unroll
  for (int off = 32; off; off >>= 1) acc += __shfl_xor(acc, off);
  if (lane == 0) v[row] = acc;
}

// ---------------------------------------------------------------------------
// Partial sums for w1[e] = sum_d Wq[d,e]*bk[d], w2[e] = sum_d Wk[d,e]*bq[d],
// plus c = bq.bk and the zeros vector. Deterministic (no atomics).
__global__ __launch_bounds__(256) void wpart_kernel(
    const float* __restrict__ Wq, const float* __restrict__ Wk,
    const float* __restrict__ bq, const float* __restrict__ bk,
    float* __restrict__ w1p, float* __restrict__ w2p,
    float* __restrict__ cbuf, float* __restrict__ zeros) {
  const int b = blockIdx.x, t = threadIdx.x;
  if (b < 32) {
    const int dc = b >> 2, e = (b & 3) * 256 + t;
    float s = 0.f;
    for (int d = dc * 128; d < dc * 128 + 128; ++d) s += Wq[(long)d * 1024 + e] * bk[d];
    w1p[dc * 1024 + e] = s;
  } else if (b < 64) {
    const int dc = (b - 32) >> 2, e = ((b - 32) & 3) * 256 + t;
    float s = 0.f;
    for (int d = dc * 128; d < dc * 128 + 128; ++d) s += Wk[(long)d * 1024 + e] * bq[d];
    w2p[dc * 1024 + e] = s;
  } else {
    for (int i = t; i < 1024; i += 256) zeros[i] = 0.f;
    float s = 0.f;
    for (int i = t; i < 1024; i += 256) s += bq[i] * bk[i];
#pragma unroll
    for (int off = 32; off; off >>= 1) s += __shfl_xor(s, off);
    __shared__ float red[4];
    if ((t & 63) == 0) red[t >> 6] = s;
    __syncthreads();
    if (t == 0) cbuf[0] = red[0] + red[1] + red[2] + red[3];
  }
}

__global__ __launch_bounds__(256) void wreduce_kernel(
    const float* __restrict__ w1p, const float* __restrict__ w2p,
    float* __restrict__ w1, float* __restrict__ w2) {
  const int b = blockIdx.x, t = threadIdx.x;
  if (b < 4) {
    const int e = b * 256 + t;
    float s = 0.f;
#pragma unroll
    for (int dc = 0; dc < 8; ++dc) s += w1p[dc * 1024 + e];
    w1[e] = s;
  } else {
    const int e = (b - 4) * 256 + t;
    float s = 0.f;
#pragma unroll
    for (int dc = 0; dc < 8; ++dc) s += w2p[dc * 1024 + e];
    w2[e] = s;
  }
}

// ---------------------------------------------------------------------------
// MT[j,d] = sum_e Wk[e,j] * Wq[e,d]  (= (Wq^T Wk)^T), fp32 accumulate,
// split-bf16 output. 64x64 tile per block, grid 16x16, 256 thr (4x4/thread).
__global__ __launch_bounds__(256) void mt_split(
    const float* __restrict__ Wk, const float* __restrict__ Wq,
    bf16* __restrict__ MTh, bf16* __restrict__ MTl) {
  __shared__ float sK[64][64], sQ[64][64];
  const int t = threadIdx.x;
  const int j0 = blockIdx.y * 64, d0 = blockIdx.x * 64;
  const int tj = t >> 4, td = t & 15;
  float acc[4][4] = {};
  for (int e0 = 0; e0 < 1024; e0 += 64) {
    __syncthreads();
#pragma unroll
    for (int it = 0; it < 4; ++it) {
      const int r = (t >> 4) + it * 16, c4 = (t & 15) * 4;
      *(f32x4*)&sK[r][c4] = *(const f32x4*)&Wk[(long)(e0 + r) * 1024 + j0 + c4];
      *(f32x4*)&sQ[r][c4] = *(const f32x4*)&Wq[(long)(e0 + r) * 1024 + d0 + c4];
    }
    __syncthreads();
#pragma unroll 4
    for (int e = 0; e < 64; ++e) {
      f32x4 a = *(const f32x4*)&sK[e][tj * 4];
      f32x4 b = *(const f32x4*)&sQ[e][td * 4];
#pragma unroll
      for (int i = 0; i < 4; ++i)
#pragma unroll
        for (int j = 0; j < 4; ++j)
          acc[i][j] += a[i] * b[j];
    }
  }
#pragma unroll
  for (int i = 0; i < 4; ++i) {
    const long row = j0 + tj * 4 + i;
#pragma unroll
    for (int j = 0; j < 4; ++j) {
      const float c = acc[i][j];
      const bf16 h = (bf16)c;
      const long idx = row * 1024 + d0 + td * 4 + j;
      MTh[idx] = h;
      MTl[idx] = (bf16)(c - (float)h);
    }
  }
}

// ---------------------------------------------------------------------------
// value [b][t][d] fp32 -> valueT [b][d][t] bf16
__global__ __launch_bounds__(256) void transpose_convert(
    const float* __restrict__ v, bf16* __restrict__ vT) {
  __shared__ float tile[32][33];
  const int b = blockIdx.z;
  const int t0 = blockIdx.y * 32, d0 = blockIdx.x * 32;
  const int tx = threadIdx.x & 31, ty = threadIdx.x >> 5;
  const float* src = v + (long)b * S * D;
#pragma unroll
  for (int i = 0; i < 4; ++i)
    tile[ty + i * 8][tx] = src[(long)(t0 + ty + i * 8) * D + d0 + tx];
  __syncthreads();
  bf16* dst = vT + (long)b * D * S;
#pragma unroll
  for (int i = 0; i < 4; ++i)
    dst[(long)(d0 + ty + i * 8) * S + t0 + tx] = (bf16)tile[tx][ty + i * 8];
}

// ---------------------------------------------------------------------------
// Split-bf16 GEMM on mfma_f32_32x32x16_bf16 (verbatim R5 structure).
// BM=BN=256, BK=32, 512 thr (8 waves 2x4, 128x64/wave = 4x2 frags).
// LDS: 2 bufs x {Ah,Al,Bh,Bl} x 16KB = 128 KB. 3 phases/K-tile (hh, hl, lh).
// EPI=0: split-bf16 out + col bias. EPI=1: fp32 out + attn_bias + v1+v2+c.
template <int EPI>
__global__ __launch_bounds__(512, 2) void gemm32_split(
    const bf16* __restrict__ Ah_g, const bf16* __restrict__ Al_g, long a_bs,
    const bf16* __restrict__ Bh_g, const bf16* __restrict__ Bl_g, long b_bs,
    const float* __restrict__ bias,
    bf16* __restrict__ Ch, bf16* __restrict__ Cl,
    float* __restrict__ Cf, long c_bs,
    const float* __restrict__ v1, const float* __restrict__ v2,
    const float* __restrict__ cvec) {
  __shared__ bf16 lds[2 * 4 * ARR];   // 128 KB

  const int tid = threadIdx.x;
  const int lane = tid & 63, wid = tid >> 6;
  const int wr = wid >> 2, wc = wid & 3;          // 2x4 wave grid
  const int lr = lane & 31;                       // row/col within 32-frag
  const int lk = lane >> 5;                       // k-half (0,1)

  // T1 bijective XCD swizzle (nwg=256)
  const int w = blockIdx.x;
  const int swz = (w & 7) * 32 + (w >> 3);
  int z, by, bx;
  if constexpr (EPI == 0) { z = 0; by = swz >> 2; bx = swz & 3; }
  else { z = swz >> 4; by = (swz >> 2) & 3; bx = swz & 3; }
  const long brow = (long)by * GBM, bcol = (long)bx * GBN;

  const bf16* A_h = Ah_g + (long)z * a_bs;
  const bf16* A_l = Al_g + (long)z * a_bs;
  const bf16* B_h = Bh_g + (long)z * b_bs;
  const bf16* B_l = Bl_g + (long)z * b_bs;

  const int srow = tid >> 2;                                  // 0..127
  const int csw = ((tid & 3) ^ ((srow >> 1) & 3)) * 8;        // source pre-swizzle
  const long asrc = (brow + srow) * 1024 + csw;
  const long bsrc = (bcol + srow) * 1024 + csw;
  const int dstoff = wid * 512;                               // wave-uniform base

  // fragment read offsets: row r, k-slice s: chunk = (2s+lk) ^ ((r>>1)&3)
  int aoff[4][2], boff[2][2];
#pragma unroll
  for (int i = 0; i < 4; ++i) {
    const int r = wr * 128 + i * 32 + lr;
#pragma unroll
    for (int s = 0; s < 2; ++s)
      aoff[i][s] = r * 32 + (((2 * s + lk) ^ ((r >> 1) & 3)) * 8);
  }
#pragma unroll
  for (int j = 0; j < 2; ++j) {
    const int r = wc * 64 + j * 32 + lr;
#pragma unroll
    for (int s = 0; s < 2; ++s)
      boff[j][s] = r * 32 + (((2 * s + lk) ^ ((r >> 1) & 3)) * 8);
  }

  f32x16 acc[4][2] = {};
  bf16x8 ah[4][2], al[4][2], bh[2][2], bl[2][2];

#define STG(slot, arr, base, koff, rr) \
  stage16((base) + (koff) + (long)(rr) * 131072, \
          lds + ((slot) * 4 + (arr)) * ARR + (rr) * 4096 + dstoff)

#define CLUSTER(AF, BF) \
  __builtin_amdgcn_s_setprio(1); \
  _Pragma("unroll") \
  for (int s = 0; s < 2; ++s) \
    _Pragma("unroll") \
    for (int i = 0; i < 4; ++i) \
      _Pragma("unroll") \
      for (int j = 0; j < 2; ++j) \
        acc[i][j] = __builtin_amdgcn_mfma_f32_32x32x16_bf16(AF[i][s], BF[j][s], acc[i][j], 0, 0, 0); \
  __builtin_amdgcn_s_setprio(0)

  // ---- prologue: stage tile 0 (order Ah,Bh,Bl,Al); publish Ah,Bh
  STG(0, 0, A_h + asrc, 0, 0); STG(0, 0, A_h + asrc, 0, 1);
  STG(0, 2, B_h + bsrc, 0, 0); STG(0, 2, B_h + bsrc, 0, 1);
  STG(0, 3, B_l + bsrc, 0, 0); STG(0, 3, B_l + bsrc, 0, 1);
  STG(0, 1, A_l + asrc, 0, 0); STG(0, 1, A_l + asrc, 0, 1);
  VMCNT(4);          // Ah0,Bh0 retired; Bl0,Al0 in flight
  SBARRIER;

  for (int t = 0; t < NTK; ++t) {
    const int cur = t & 1, nxt = cur ^ 1;
    const long kn = (long)(t + 1) * GBK;
    const bool pf = (t + 1 < NTK);
    const bf16* lA_h = lds + (cur * 4 + 0) * ARR;
    const bf16* lA_l = lds + (cur * 4 + 1) * ARR;
    const bf16* lB_h = lds + (cur * 4 + 2) * ARR;
    const bf16* lB_l = lds + (cur * 4 + 3) * ARR;

    // ---- P1: read ah,bh | stage Ah',Bh' | vmcnt(6) | bar | lgkm0 | hh
#pragma unroll
    for (int i = 0; i < 4; ++i)
#pragma unroll
      for (int s = 0; s < 2; ++s) ah[i][s] = *(const bf16x8*)&lA_h[aoff[i][s]];
#pragma unroll
    for (int j = 0; j < 2; ++j)
#pragma unroll
      for (int s = 0; s < 2; ++s) bh[j][s] = *(const bf16x8*)&lB_h[boff[j][s]];
    if (pf) {
      STG(nxt, 0, A_h + asrc, kn, 0); STG(nxt, 0, A_h + asrc, kn, 1);
      STG(nxt, 2, B_h + bsrc, kn, 0); STG(nxt, 2, B_h + bsrc, kn, 1);
      VMCNT(6);      // retires Bl(t)
    } else {
      VMCNT(2);      // tail: retires Bl(t), Al(t) still in flight
    }
    SBARRIER; LGKM(0); SB0;
    CLUSTER(ah, bh);
    SBARRIER;

    // ---- P2: read bl | stage Bl' | vmcnt(6) | bar | lgkm0 | hl
#pragma unroll
    for (int j = 0; j < 2; ++j)
#pragma unroll
      for (int s = 0; s < 2; ++s) bl[j][s] = *(const bf16x8*)&lB_l[boff[j][s]];
    if (pf) {
      STG(nxt, 3, B_l + bsrc, kn, 0); STG(nxt, 3, B_l + bsrc, kn, 1);
      VMCNT(6);      // retires Al(t)
    } else {
      VMCNT(0);      // tail: retires Al(t)
    }
    SBARRIER; LGKM(0); SB0;
    CLUSTER(ah, bl);
    SBARRIER;

    // ---- P3: read al | stage Al' | vmcnt(4) | bar | lgkm0 | lh
#pragma unroll
    for (int i = 0; i < 4; ++i)
#pragma unroll
      for (int s = 0; s < 2; ++s) al[i][s] = *(const bf16x8*)&lA_l[aoff[i][s]];
    if (pf) {
      STG(nxt, 1, A_l + asrc, kn, 0); STG(nxt, 1, A_l + asrc, kn, 1);
      VMCNT(4);      // retires Ah',Bh' (visible for P1(t+1))
    }
    SBARRIER; LGKM(0); SB0;
    CLUSTER(al, bh);
    SBARRIER;
  }
#undef STG
#undef CLUSTER

  // Epilogue. 32x32 C/D frag [m74/m101]: col = lane&31,
  // row = (reg&3) + 8*(reg>>2) + 4*(lane>>5)
  if constexpr (EPI == 0) {
#pragma unroll
    for (int j = 0; j < 2; ++j) {
      const long col = bcol + wc * 64 + j * 32 + lr;
      const float bv = bias[col];
#pragma unroll
      for (int i = 0; i < 4; ++i) {
        const long row0 = brow + wr * 128 + i * 32 + 4 * lk;
#pragma unroll
        for (int r = 0; r < 16; ++r) {
          const long row = row0 + (r & 3) + 8 * (r >> 2);
          const float c = acc[i][j][r] + bv;
          const bf16 h = (bf16)c;
          const bf16 l = (bf16)(c - (float)h);
          const long idx = row * 1024 + col;
          Ch[idx] = h;
          Cl[idx] = l;
        }
      }
    }
  } else {
    float* Cz = Cf + (long)z * c_bs;
    const float cc = cvec[0];
    const float* vz1 = v1 + (long)z * 1024;
    const float* vz2 = v2 + (long)z * 1024;
#pragma unroll
    for (int j = 0; j < 2; ++j) {
      const long col = bcol + wc * 64 + j * 32 + lr;
      const float v2c = vz2[col] + cc;
#pragma unroll
      for (int i = 0; i < 4; ++i) {
        const long row0 = brow + wr * 128 + i * 32 + 4 * lk;
#pragma unroll
        for (int r = 0; r < 16; ++r) {
          const long row = row0 + (r & 3) + 8 * (r >> 2);
          Cz[row * 1024 + col] = acc[i][j][r] + bias[row * 1024 + col] + vz1[row] + v2c;
        }
      }
    }
  }
}

// ---------------------------------------------------------------------------
// Plain bf16 GEMM (PV), R3 structure: 2 bufs x {A,B} = 64KB; per K-tile
// stage t+1 ; vmcnt(4) ; barrier ; 12 reads + 32 MFMA ; barrier.
__global__ __launch_bounds__(512, 2) void gemm8_plain(
    const bf16* __restrict__ A_g, long a_bs,
    const bf16* __restrict__ B_g, long b_bs,
    float* __restrict__ C, long c_bs) {
  __shared__ bf16 lds[2 * 2 * ARR];   // 64 KB

  const int tid = threadIdx.x;
  const int lane = tid & 63, wid = tid >> 6;
  const int wr = wid >> 2, wc = wid & 3;
  const int fr = lane & 15, fq = lane >> 4;
  const int fsw = (fr >> 1) & 3;

  const int w = blockIdx.x;
  const int swz = (w & 7) * 32 + (w >> 3);
  const int z = swz >> 4, by = (swz >> 2) & 3, bx = swz & 3;
  const long brow = (long)by * GBM, bcol = (long)bx * GBN;

  const bf16* A = A_g + (long)z * a_bs;
  const bf16* B = B_g + (long)z * b_bs;

  const int srow = tid >> 2;
  const int csw = ((tid & 3) ^ ((srow >> 1) & 3)) * 8;
  const long asrc = (brow + srow) * 1024 + csw;
  const long bsrc = (bcol + srow) * 1024 + csw;
  const int dstoff = wid * 512;

  const int aoffb = (wr * 128 + fr) * 32 + (fq ^ fsw) * 8;
  const int boffb = (wc * 64 + fr) * 32 + (fq ^ fsw) * 8;

  f32x4 acc[8][4] = {};

#define STG2(slot, arr, base, koff, rr) \
  stage16((base) + (koff) + (long)(rr) * 131072, \
          lds + ((slot) * 2 + (arr)) * ARR + (rr) * 4096 + dstoff)

  STG2(0, 0, A + asrc, 0, 0); STG2(0, 0, A + asrc, 0, 1);
  STG2(0, 1, B + bsrc, 0, 0); STG2(0, 1, B + bsrc, 0, 1);

  for (int t = 0; t < NTK; ++t) {
    const int cur = t & 1, nxt = cur ^ 1;
    const bf16* lA = lds + (cur * 2 + 0) * ARR;
    const bf16* lB = lds + (cur * 2 + 1) * ARR;

    if (t + 1 < NTK) {
      const long kn = (long)(t + 1) * GBK;
      STG2(nxt, 0, A + asrc, kn, 0); STG2(nxt, 0, A + asrc, kn, 1);
      STG2(nxt, 1, B + bsrc, kn, 0); STG2(nxt, 1, B + bsrc, kn, 1);
      VMCNT(4);
    } else {
      VMCNT(0);
    }
    SB0;
    SBARRIER;

    bf16x8 ah[8], bh[4];
#pragma unroll
    for (int m = 0; m < 8; ++m) ah[m] = *(const bf16x8*)&lA[aoffb + m * 512];
#pragma unroll
    for (int n = 0; n < 4; ++n) bh[n] = *(const bf16x8*)&lB[boffb + n * 512];
#pragma unroll
    for (int n = 0; n < 4; ++n)
#pragma unroll
      for (int m = 0; m < 8; ++m)
        acc[m][n] = __builtin_amdgcn_mfma_f32_16x16x32_bf16(ah[m], bh[n], acc[m][n], 0, 0, 0);

    SBARRIER;
  }
#undef STG2

  float* Cz = C + (long)z * c_bs;
#pragma unroll
  for (int n = 0; n < 4; ++n) {
    const long col = bcol + wc * 64 + n * 16 + fr;
#pragma unroll
    for (int m = 0; m < 8; ++m) {
      const long row0 = brow + wr * 128 + m * 16 + fq * 4;
#pragma unroll
      for (int j = 0; j < 4; ++j)
        Cz[(row0 + j) * 1024 + col] = acc[m][n][j];
    }
  }
}

// ---------------------------------------------------------------------------
__global__ __launch_bounds__(256) void softmax_rows(
    float* __restrict__ attn, bf16* __restrict__ attn_bf) {
  const long row = blockIdx.x;
  float* p = attn + row * 1024;
  const int tid = threadIdx.x, lane = tid & 63, wid = tid >> 6;

  f32x4 x = ((const f32x4*)p)[tid];
  float m = fmaxf(fmaxf(x[0], x[1]), fmaxf(x[2], x[3]));
#pragma unroll
  for (int off = 32; off; off >>= 1) m = fmaxf(m, __shfl_xor(m, off));
  __shared__ float redm[4];
  if (lane == 0) redm[wid] = m;
  __syncthreads();
  m = fmaxf(fmaxf(redm[0], redm[1]), fmaxf(redm[2], redm[3]));

  f32x4 e;
#pragma unroll
  for (int j = 0; j < 4; ++j) e[j] = __expf(x[j] - m);
  float s = e[0] + e[1] + e[2] + e[3];
#pragma unroll
  for (int off = 32; off; off >>= 1) s += __shfl_xor(s, off);
  __shared__ float reds[4];
  if (lane == 0) reds[wid] = s;
  __syncthreads();
  s = reds[0] + reds[1] + reds[2] + reds[3];

  const float inv = 1.0f / s;
  f32x4 r;
  bf16x4 rb;
#pragma unroll
  for (int j = 0; j < 4; ++j) {
    r[j] = e[j] * inv;
    rb[j] = (bf16)r[j];
  }
  ((f32x4*)p)[tid] = r;
  ((bf16x4*)(attn_bf + row * 1024))[tid] = rb;
}

// ---------------------------------------------------------------------------
extern "C" void kernel_launch(void* const* d_in, const int* in_sizes, int n_in,
                              void* d_out, int out_size, void* d_ws, size_t ws_size,
                              hipStream_t stream) {
  const float* query     = (const float*)d_in[0];
  const float* key       = (const float*)d_in[1];
  const float* value     = (const float*)d_in[2];
  const float* attn_bias = (const float*)d_in[3];
  const float* Wq        = (const float*)d_in[4];
  const float* bq        = (const float*)d_in[5];
  const float* Wk        = (const float*)d_in[6];
  const float* bk        = (const float*)d_in[7];

  float* out  = (float*)d_out;          // [16,1024,1024]
  float* attn = out + NBSD;             // [16,1024,1024]

  // ws carve (R5-topology): k, qm, valueT, attn_bf, MT+small all in ws.
  bf16* ws      = (bf16*)d_ws;
  bf16* k_hi    = ws;                   // split(key)
  bf16* k_lo    = ws + NBSD;
  bf16* qm_hi   = ws + 2 * NBSD;        // split(Q M)
  bf16* qm_lo   = ws + 3 * NBSD;
  bf16* valueT  = ws + 4 * NBSD;
  bf16* attn_bf = ws + 5 * NBSD;
  bf16* smallb  = ws + 6 * NBSD;
  bf16* MT_hi   = smallb;               // [1024,1024]
  bf16* MT_lo   = smallb + 1048576;
  float* fsm    = (float*)(smallb + 2097152);
  float* zeros  = fsm;                  // 1024
  float* w1     = fsm + 1024;           // 1024
  float* w2     = fsm + 2048;           // 1024
  float* cbuf   = fsm + 3072;           // 1
  float* v1     = fsm + 4096;           // 16384
  float* v2     = fsm + 20480;          // 16384
  float* w1p    = fsm + 36864;          // 8x1024
  float* w2p    = fsm + 45056;          // 8x1024
  // query splits live in d_out's `out` region (R5 pattern: dead before PV writes)
  bf16* q_hi = (bf16*)d_out;
  bf16* q_lo = q_hi + NBSD;

  // 1) bias-correction precompute: w1 = Wq^T bk, w2 = Wk^T bq, c, zeros
  wpart_kernel<<<65, 256, 0, stream>>>(Wq, Wk, bq, bk, w1p, w2p, cbuf, zeros);
  wreduce_kernel<<<8, 256, 0, stream>>>(w1p, w2p, w1, w2);

  // 2) split conversions with fused rank-1 dots (R5 order: q then k)
  split_convert_dot<<<4096, 256, 0, stream>>>(query, q_hi, q_lo, w1, v1);
  split_convert_dot<<<4096, 256, 0, stream>>>(key, k_hi, k_lo, w2, v2);

  // 3) MT = (Wq^T Wk)^T (sits where R5's W-converts sat)
  mt_split<<<dim3(16, 16), 256, 0, stream>>>(Wk, Wq, MT_hi, MT_lo);

  // 4) QM = query @ M  (R5-proj pattern: A from d_out, B small ws, C -> ws)
  gemm32_split<0><<<256, 512, 0, stream>>>(q_hi, q_lo, 0, MT_hi, MT_lo, 0,
                                           zeros, qm_hi, qm_lo, nullptr, 0,
                                           nullptr, nullptr, nullptr);

  // 5) value transpose
  transpose_convert<<<dim3(32, 32, 16), 256, 0, stream>>>(value, valueT);

  // 6) energy = QM K^T + attn_bias + v1[s] + v2[t] + c (R5-energy pattern)
  gemm32_split<1><<<256, 512, 0, stream>>>(qm_hi, qm_lo, (long)S * D,
                                           k_hi, k_lo, (long)S * D,
                                           attn_bias, nullptr, nullptr, attn, (long)S * S,
                                           v1, v2, cbuf);

  // 7) softmax in place + bf16 copy
  softmax_rows<<<BATCH * S, 256, 0, stream>>>(attn, attn_bf);

  // 8) out = attention @ value
  gemm8_plain<<<256, 512, 0, stream>>>(attn_bf, (long)S * S, valueT, (long)D * S,
                                       out, (long)S * D);
}

// Round 12
// 475.583 us; speedup vs baseline: 1.0158x; 1.0158x over previous
//
#include <hip/hip_runtime.h>

// ---------------------------------------------------------------------------
// RVMixtureSynthesizers: q = query@Wq^T + bq ; k = key@Wk^T + bk
//   energy = q@k^T + attn_bias ; attention = softmax(energy) ; out = attention@value
// Outputs: out [16,1024,1024] fp32, attention [16,1024,1024] fp32 (concat in d_out)
//
// R11: R9/R10 algebra (energy = Q·(Wq^T Wk)·K^T + v1 + v2 + c) with the launch
// ORDER fixed for L3 locality: each GEMM runs adjacent to its producers and
// with no unrelated dirty buffer pending, so its HBM window stays ~150 MB:
//   wpart, wreduce, conv-q, mt, transpose, QM, conv-k, energy, softmax, PV.
// Kernels byte-identical to R10.
// ---------------------------------------------------------------------------

#define AS1 __attribute__((address_space(1)))
#define AS3 __attribute__((address_space(3)))
#define VMCNT(n) asm volatile("s_waitcnt vmcnt(" #n ")" ::: "memory")
#define LGKM(n)  asm volatile("s_waitcnt lgkmcnt(" #n ")" ::: "memory")
#define SBARRIER asm volatile("s_barrier" ::: "memory")
#define SB0 __builtin_amdgcn_sched_barrier(0)

typedef __bf16 bf16;
typedef __bf16 bf16x4 __attribute__((ext_vector_type(4)));
typedef __bf16 bf16x8 __attribute__((ext_vector_type(8)));
typedef float  f32x4  __attribute__((ext_vector_type(4)));
typedef float  f32x16 __attribute__((ext_vector_type(16)));

constexpr int BATCH = 16;
constexpr int S = 1024;
constexpr int D = 1024;
constexpr long NBSD = (long)BATCH * S * D;   // 16777216

constexpr int GBM = 256, GBN = 256, GBK = 32;
constexpr int NTK = 1024 / GBK;              // 32 K-tiles
constexpr int ARR = GBM * GBK;               // 8192 elems = 16 KB per array

__device__ __forceinline__ void stage16(const bf16* src, const bf16* dst) {
  __builtin_amdgcn_global_load_lds((const AS1 void*)src, (AS3 void*)dst, 16, 0, 0);
}

// ---------------------------------------------------------------------------
// fp32 -> (hi,lo) bf16 split + fused dot with w (v[row] = row . w).
__global__ __launch_bounds__(256) void split_convert_dot(
    const float* __restrict__ in, bf16* __restrict__ hi, bf16* __restrict__ lo,
    const float* __restrict__ w, float* __restrict__ v) {
  const int wid = threadIdx.x >> 6, lane = threadIdx.x & 63;
  const long row = (long)blockIdx.x * 4 + wid;
  const f32x4* src = (const f32x4*)(in + row * 1024);
  const f32x4* w4 = (const f32x4*)w;
  float acc = 0.f;
#pragma unroll
  for (int it = 0; it < 4; ++it) {
    const int idx = it * 64 + lane;
    f32x4 x = src[idx];
    f32x4 wv = w4[idx];
    bf16x4 h, l;
#pragma unroll
    for (int j = 0; j < 4; ++j) {
      float vv = x[j];
      bf16 hh = (bf16)vv;
      h[j] = hh;
      l[j] = (bf16)(vv - (float)hh);
      acc += vv * wv[j];
    }
    *(bf16x4*)(hi + row * 1024 + idx * 4) = h;
    *(bf16x4*)(lo + row * 1024 + idx * 4) = l;
  }
#pragma unroll
  for (int off = 32; off; off >>= 1) acc += __shfl_xor(acc, off);
  if (lane == 0) v[row] = acc;
}

// ---------------------------------------------------------------------------
// Partial sums for w1[e] = sum_d Wq[d,e]*bk[d], w2[e] = sum_d Wk[d,e]*bq[d],
// plus c = bq.bk and the zeros vector. Deterministic (no atomics).
__global__ __launch_bounds__(256) void wpart_kernel(
    const float* __restrict__ Wq, const float* __restrict__ Wk,
    const float* __restrict__ bq, const float* __restrict__ bk,
    float* __restrict__ w1p, float* __restrict__ w2p,
    float* __restrict__ cbuf, float* __restrict__ zeros) {
  const int b = blockIdx.x, t = threadIdx.x;
  if (b < 32) {
    const int dc = b >> 2, e = (b & 3) * 256 + t;
    float s = 0.f;
    for (int d = dc * 128; d < dc * 128 + 128; ++d) s += Wq[(long)d * 1024 + e] * bk[d];
    w1p[dc * 1024 + e] = s;
  } else if (b < 64) {
    const int dc = (b - 32) >> 2, e = ((b - 32) & 3) * 256 + t;
    float s = 0.f;
    for (int d = dc * 128; d < dc * 128 + 128; ++d) s += Wk[(long)d * 1024 + e] * bq[d];
    w2p[dc * 1024 + e] = s;
  } else {
    for (int i = t; i < 1024; i += 256) zeros[i] = 0.f;
    float s = 0.f;
    for (int i = t; i < 1024; i += 256) s += bq[i] * bk[i];
#pragma unroll
    for (int off = 32; off; off >>= 1) s += __shfl_xor(s, off);
    __shared__ float red[4];
    if ((t & 63) == 0) red[t >> 6] = s;
    __syncthreads();
    if (t == 0) cbuf[0] = red[0] + red[1] + red[2] + red[3];
  }
}

__global__ __launch_bounds__(256) void wreduce_kernel(
    const float* __restrict__ w1p, const float* __restrict__ w2p,
    float* __restrict__ w1, float* __restrict__ w2) {
  const int b = blockIdx.x, t = threadIdx.x;
  if (b < 4) {
    const int e = b * 256 + t;
    float s = 0.f;
#pragma unroll
    for (int dc = 0; dc < 8; ++dc) s += w1p[dc * 1024 + e];
    w1[e] = s;
  } else {
    const int e = (b - 4) * 256 + t;
    float s = 0.f;
#pragma unroll
    for (int dc = 0; dc < 8; ++dc) s += w2p[dc * 1024 + e];
    w2[e] = s;
  }
}

// ---------------------------------------------------------------------------
// MT[j,d] = sum_e Wk[e,j] * Wq[e,d]  (= (Wq^T Wk)^T), fp32 accumulate,
// split-bf16 output. 64x64 tile per block, grid 16x16, 256 thr (4x4/thread).
__global__ __launch_bounds__(256) void mt_split(
    const float* __restrict__ Wk, const float* __restrict__ Wq,
    bf16* __restrict__ MTh, bf16* __restrict__ MTl) {
  __shared__ float sK[64][64], sQ[64][64];
  const int t = threadIdx.x;
  const int j0 = blockIdx.y * 64, d0 = blockIdx.x * 64;
  const int tj = t >> 4, td = t & 15;
  float acc[4][4] = {};
  for (int e0 = 0; e0 < 1024; e0 += 64) {
    __syncthreads();
#pragma unroll
    for (int it = 0; it < 4; ++it) {
      const int r = (t >> 4) + it * 16, c4 = (t & 15) * 4;
      *(f32x4*)&sK[r][c4] = *(const f32x4*)&Wk[(long)(e0 + r) * 1024 + j0 + c4];
      *(f32x4*)&sQ[r][c4] = *(const f32x4*)&Wq[(long)(e0 + r) * 1024 + d0 + c4];
    }
    __syncthreads();
#pragma unroll 4
    for (int e = 0; e < 64; ++e) {
      f32x4 a = *(const f32x4*)&sK[e][tj * 4];
      f32x4 b = *(const f32x4*)&sQ[e][td * 4];
#pragma unroll
      for (int i = 0; i < 4; ++i)
#pragma unroll
        for (int j = 0; j < 4; ++j)
          acc[i][j] += a[i] * b[j];
    }
  }
#pragma unroll
  for (int i = 0; i < 4; ++i) {
    const long row = j0 + tj * 4 + i;
#pragma unroll
    for (int j = 0; j < 4; ++j) {
      const float c = acc[i][j];
      const bf16 h = (bf16)c;
      const long idx = row * 1024 + d0 + td * 4 + j;
      MTh[idx] = h;
      MTl[idx] = (bf16)(c - (float)h);
    }
  }
}

// ---------------------------------------------------------------------------
// value [b][t][d] fp32 -> valueT [b][d][t] bf16
__global__ __launch_bounds__(256) void transpose_convert(
    const float* __restrict__ v, bf16* __restrict__ vT) {
  __shared__ float tile[32][33];
  const int b = blockIdx.z;
  const int t0 = blockIdx.y * 32, d0 = blockIdx.x * 32;
  const int tx = threadIdx.x & 31, ty = threadIdx.x >> 5;
  const float* src = v + (long)b * S * D;
#pragma unroll
  for (int i = 0; i < 4; ++i)
    tile[ty + i * 8][tx] = src[(long)(t0 + ty + i * 8) * D + d0 + tx];
  __syncthreads();
  bf16* dst = vT + (long)b * D * S;
#pragma unroll
  for (int i = 0; i < 4; ++i)
    dst[(long)(d0 + ty + i * 8) * S + t0 + tx] = (bf16)tile[tx][ty + i * 8];
}

// ---------------------------------------------------------------------------
// Split-bf16 GEMM on mfma_f32_32x32x16_bf16 (verbatim R5 structure).
// BM=BN=256, BK=32, 512 thr (8 waves 2x4, 128x64/wave = 4x2 frags).
// LDS: 2 bufs x {Ah,Al,Bh,Bl} x 16KB = 128 KB. 3 phases/K-tile (hh, hl, lh).
// EPI=0: split-bf16 out + col bias. EPI=1: fp32 out + attn_bias + v1+v2+c.
template <int EPI>
__global__ __launch_bounds__(512, 2) void gemm32_split(
    const bf16* __restrict__ Ah_g, const bf16* __restrict__ Al_g, long a_bs,
    const bf16* __restrict__ Bh_g, const bf16* __restrict__ Bl_g, long b_bs,
    const float* __restrict__ bias,
    bf16* __restrict__ Ch, bf16* __restrict__ Cl,
    float* __restrict__ Cf, long c_bs,
    const float* __restrict__ v1, const float* __restrict__ v2,
    const float* __restrict__ cvec) {
  __shared__ bf16 lds[2 * 4 * ARR];   // 128 KB

  const int tid = threadIdx.x;
  const int lane = tid & 63, wid = tid >> 6;
  const int wr = wid >> 2, wc = wid & 3;          // 2x4 wave grid
  const int lr = lane & 31;                       // row/col within 32-frag
  const int lk = lane >> 5;                       // k-half (0,1)

  // T1 bijective XCD swizzle (nwg=256)
  const int w = blockIdx.x;
  const int swz = (w & 7) * 32 + (w >> 3);
  int z, by, bx;
  if constexpr (EPI == 0) { z = 0; by = swz >> 2; bx = swz & 3; }
  else { z = swz >> 4; by = (swz >> 2) & 3; bx = swz & 3; }
  const long brow = (long)by * GBM, bcol = (long)bx * GBN;

  const bf16* A_h = Ah_g + (long)z * a_bs;
  const bf16* A_l = Al_g + (long)z * a_bs;
  const bf16* B_h = Bh_g + (long)z * b_bs;
  const bf16* B_l = Bl_g + (long)z * b_bs;

  const int srow = tid >> 2;                                  // 0..127
  const int csw = ((tid & 3) ^ ((srow >> 1) & 3)) * 8;        // source pre-swizzle
  const long asrc = (brow + srow) * 1024 + csw;
  const long bsrc = (bcol + srow) * 1024 + csw;
  const int dstoff = wid * 512;                               // wave-uniform base

  // fragment read offsets: row r, k-slice s: chunk = (2s+lk) ^ ((r>>1)&3)
  int aoff[4][2], boff[2][2];
#pragma unroll
  for (int i = 0; i < 4; ++i) {
    const int r = wr * 128 + i * 32 + lr;
#pragma unroll
    for (int s = 0; s < 2; ++s)
      aoff[i][s] = r * 32 + (((2 * s + lk) ^ ((r >> 1) & 3)) * 8);
  }
#pragma unroll
  for (int j = 0; j < 2; ++j) {
    const int r = wc * 64 + j * 32 + lr;
#pragma unroll
    for (int s = 0; s < 2; ++s)
      boff[j][s] = r * 32 + (((2 * s + lk) ^ ((r >> 1) & 3)) * 8);
  }

  f32x16 acc[4][2] = {};
  bf16x8 ah[4][2], al[4][2], bh[2][2], bl[2][2];

#define STG(slot, arr, base, koff, rr) \
  stage16((base) + (koff) + (long)(rr) * 131072, \
          lds + ((slot) * 4 + (arr)) * ARR + (rr) * 4096 + dstoff)

#define CLUSTER(AF, BF) \
  __builtin_amdgcn_s_setprio(1); \
  _Pragma("unroll") \
  for (int s = 0; s < 2; ++s) \
    _Pragma("unroll") \
    for (int i = 0; i < 4; ++i) \
      _Pragma("unroll") \
      for (int j = 0; j < 2; ++j) \
        acc[i][j] = __builtin_amdgcn_mfma_f32_32x32x16_bf16(AF[i][s], BF[j][s], acc[i][j], 0, 0, 0); \
  __builtin_amdgcn_s_setprio(0)

  // ---- prologue: stage tile 0 (order Ah,Bh,Bl,Al); publish Ah,Bh
  STG(0, 0, A_h + asrc, 0, 0); STG(0, 0, A_h + asrc, 0, 1);
  STG(0, 2, B_h + bsrc, 0, 0); STG(0, 2, B_h + bsrc, 0, 1);
  STG(0, 3, B_l + bsrc, 0, 0); STG(0, 3, B_l + bsrc, 0, 1);
  STG(0, 1, A_l + asrc, 0, 0); STG(0, 1, A_l + asrc, 0, 1);
  VMCNT(4);          // Ah0,Bh0 retired; Bl0,Al0 in flight
  SBARRIER;

  for (int t = 0; t < NTK; ++t) {
    const int cur = t & 1, nxt = cur ^ 1;
    const long kn = (long)(t + 1) * GBK;
    const bool pf = (t + 1 < NTK);
    const bf16* lA_h = lds + (cur * 4 + 0) * ARR;
    const bf16* lA_l = lds + (cur * 4 + 1) * ARR;
    const bf16* lB_h = lds + (cur * 4 + 2) * ARR;
    const bf16* lB_l = lds + (cur * 4 + 3) * ARR;

    // ---- P1: read ah,bh | stage Ah',Bh' | vmcnt(6) | bar | lgkm0 | hh
#pragma unroll
    for (int i = 0; i < 4; ++i)
#pragma unroll
      for (int s = 0; s < 2; ++s) ah[i][s] = *(const bf16x8*)&lA_h[aoff[i][s]];
#pragma unroll
    for (int j = 0; j < 2; ++j)
#pragma unroll
      for (int s = 0; s < 2; ++s) bh[j][s] = *(const bf16x8*)&lB_h[boff[j][s]];
    if (pf) {
      STG(nxt, 0, A_h + asrc, kn, 0); STG(nxt, 0, A_h + asrc, kn, 1);
      STG(nxt, 2, B_h + bsrc, kn, 0); STG(nxt, 2, B_h + bsrc, kn, 1);
      VMCNT(6);      // retires Bl(t)
    } else {
      VMCNT(2);      // tail: retires Bl(t), Al(t) still in flight
    }
    SBARRIER; LGKM(0); SB0;
    CLUSTER(ah, bh);
    SBARRIER;

    // ---- P2: read bl | stage Bl' | vmcnt(6) | bar | lgkm0 | hl
#pragma unroll
    for (int j = 0; j < 2; ++j)
#pragma unroll
      for (int s = 0; s < 2; ++s) bl[j][s] = *(const bf16x8*)&lB_l[boff[j][s]];
    if (pf) {
      STG(nxt, 3, B_l + bsrc, kn, 0); STG(nxt, 3, B_l + bsrc, kn, 1);
      VMCNT(6);      // retires Al(t)
    } else {
      VMCNT(0);      // tail: retires Al(t)
    }
    SBARRIER; LGKM(0); SB0;
    CLUSTER(ah, bl);
    SBARRIER;

    // ---- P3: read al | stage Al' | vmcnt(4) | bar | lgkm0 | lh
#pragma unroll
    for (int i = 0; i < 4; ++i)
#pragma unroll
      for (int s = 0; s < 2; ++s) al[i][s] = *(const bf16x8*)&lA_l[aoff[i][s]];
    if (pf) {
      STG(nxt, 1, A_l + asrc, kn, 0); STG(nxt, 1, A_l + asrc, kn, 1);
      VMCNT(4);      // retires Ah',Bh' (visible for P1(t+1))
    }
    SBARRIER; LGKM(0); SB0;
    CLUSTER(al, bh);
    SBARRIER;
  }
#undef STG
#undef CLUSTER

  // Epilogue. 32x32 C/D frag [m74/m101]: col = lane&31,
  // row = (reg&3) + 8*(reg>>2) + 4*(lane>>5)
  if constexpr (EPI == 0) {
#pragma unroll
    for (int j = 0; j < 2; ++j) {
      const long col = bcol + wc * 64 + j * 32 + lr;
      const float bv = bias[col];
#pragma unroll
      for (int i = 0; i < 4; ++i) {
        const long row0 = brow + wr * 128 + i * 32 + 4 * lk;
#pragma unroll
        for (int r = 0; r < 16; ++r) {
          const long row = row0 + (r & 3) + 8 * (r >> 2);
          const float c = acc[i][j][r] + bv;
          const bf16 h = (bf16)c;
          const bf16 l = (bf16)(c - (float)h);
          const long idx = row * 1024 + col;
          Ch[idx] = h;
          Cl[idx] = l;
        }
      }
    }
  } else {
    float* Cz = Cf + (long)z * c_bs;
    const float cc = cvec[0];
    const float* vz1 = v1 + (long)z * 1024;
    const float* vz2 = v2 + (long)z * 1024;
#pragma unroll
    for (int j = 0; j < 2; ++j) {
      const long col = bcol + wc * 64 + j * 32 + lr;
      const float v2c = vz2[col] + cc;
#pragma unroll
      for (int i = 0; i < 4; ++i) {
        const long row0 = brow + wr * 128 + i * 32 + 4 * lk;
#pragma unroll
        for (int r = 0; r < 16; ++r) {
          const long row = row0 + (r & 3) + 8 * (r >> 2);
          Cz[row * 1024 + col] = acc[i][j][r] + bias[row * 1024 + col] + vz1[row] + v2c;
        }
      }
    }
  }
}

// ---------------------------------------------------------------------------
// Plain bf16 GEMM (PV), R3 structure: 2 bufs x {A,B} = 64KB; per K-tile
// stage t+1 ; vmcnt(4) ; barrier ; 12 reads + 32 MFMA ; barrier.
__global__ __launch_bounds__(512, 2) void gemm8_plain(
    const bf16* __restrict__ A_g, long a_bs,
    const bf16* __restrict__ B_g, long b_bs,
    float* __restrict__ C, long c_bs) {
  __shared__ bf16 lds[2 * 2 * ARR];   // 64 KB

  const int tid = threadIdx.x;
  const int lane = tid & 63, wid = tid >> 6;
  const int wr = wid >> 2, wc = wid & 3;
  const int fr = lane & 15, fq = lane >> 4;
  const int fsw = (fr >> 1) & 3;

  const int w = blockIdx.x;
  const int swz = (w & 7) * 32 + (w >> 3);
  const int z = swz >> 4, by = (swz >> 2) & 3, bx = swz & 3;
  const long brow = (long)by * GBM, bcol = (long)bx * GBN;

  const bf16* A = A_g + (long)z * a_bs;
  const bf16* B = B_g + (long)z * b_bs;

  const int srow = tid >> 2;
  const int csw = ((tid & 3) ^ ((srow >> 1) & 3)) * 8;
  const long asrc = (brow + srow) * 1024 + csw;
  const long bsrc = (bcol + srow) * 1024 + csw;
  const int dstoff = wid * 512;

  const int aoffb = (wr * 128 + fr) * 32 + (fq ^ fsw) * 8;
  const int boffb = (wc * 64 + fr) * 32 + (fq ^ fsw) * 8;

  f32x4 acc[8][4] = {};

#define STG2(slot, arr, base, koff, rr) \
  stage16((base) + (koff) + (long)(rr) * 131072, \
          lds + ((slot) * 2 + (arr)) * ARR + (rr) * 4096 + dstoff)

  STG2(0, 0, A + asrc, 0, 0); STG2(0, 0, A + asrc, 0, 1);
  STG2(0, 1, B + bsrc, 0, 0); STG2(0, 1, B + bsrc, 0, 1);

  for (int t = 0; t < NTK; ++t) {
    const int cur = t & 1, nxt = cur ^ 1;
    const bf16* lA = lds + (cur * 2 + 0) * ARR;
    const bf16* lB = lds + (cur * 2 + 1) * ARR;

    if (t + 1 < NTK) {
      const long kn = (long)(t + 1) * GBK;
      STG2(nxt, 0, A + asrc, kn, 0); STG2(nxt, 0, A + asrc, kn, 1);
      STG2(nxt, 1, B + bsrc, kn, 0); STG2(nxt, 1, B + bsrc, kn, 1);
      VMCNT(4);
    } else {
      VMCNT(0);
    }
    SB0;
    SBARRIER;

    bf16x8 ah[8], bh[4];
#pragma unroll
    for (int m = 0; m < 8; ++m) ah[m] = *(const bf16x8*)&lA[aoffb + m * 512];
#pragma unroll
    for (int n = 0; n < 4; ++n) bh[n] = *(const bf16x8*)&lB[boffb + n * 512];
#pragma unroll
    for (int n = 0; n < 4; ++n)
#pragma unroll
      for (int m = 0; m < 8; ++m)
        acc[m][n] = __builtin_amdgcn_mfma_f32_16x16x32_bf16(ah[m], bh[n], acc[m][n], 0, 0, 0);

    SBARRIER;
  }
#undef STG2

  float* Cz = C + (long)z * c_bs;
#pragma unroll
  for (int n = 0; n < 4; ++n) {
    const long col = bcol + wc * 64 + n * 16 + fr;
#pragma unroll
    for (int m = 0; m < 8; ++m) {
      const long row0 = brow + wr * 128 + m * 16 + fq * 4;
#pragma unroll
      for (int j = 0; j < 4; ++j)
        Cz[(row0 + j) * 1024 + col] = acc[m][n][j];
    }
  }
}

// ---------------------------------------------------------------------------
__global__ __launch_bounds__(256) void softmax_rows(
    float* __restrict__ attn, bf16* __restrict__ attn_bf) {
  const long row = blockIdx.x;
  float* p = attn + row * 1024;
  const int tid = threadIdx.x, lane = tid & 63, wid = tid >> 6;

  f32x4 x = ((const f32x4*)p)[tid];
  float m = fmaxf(fmaxf(x[0], x[1]), fmaxf(x[2], x[3]));
#pragma unroll
  for (int off = 32; off; off >>= 1) m = fmaxf(m, __shfl_xor(m, off));
  __shared__ float redm[4];
  if (lane == 0) redm[wid] = m;
  __syncthreads();
  m = fmaxf(fmaxf(redm[0], redm[1]), fmaxf(redm[2], redm[3]));

  f32x4 e;
#pragma unroll
  for (int j = 0; j < 4; ++j) e[j] = __expf(x[j] - m);
  float s = e[0] + e[1] + e[2] + e[3];
#pragma unroll
  for (int off = 32; off; off >>= 1) s += __shfl_xor(s, off);
  __shared__ float reds[4];
  if (lane == 0) reds[wid] = s;
  __syncthreads();
  s = reds[0] + reds[1] + reds[2] + reds[3];

  const float inv = 1.0f / s;
  f32x4 r;
  bf16x4 rb;
#pragma unroll
  for (int j = 0; j < 4; ++j) {
    r[j] = e[j] * inv;
    rb[j] = (bf16)r[j];
  }
  ((f32x4*)p)[tid] = r;
  ((bf16x4*)(attn_bf + row * 1024))[tid] = rb;
}

// ---------------------------------------------------------------------------
extern "C" void kernel_launch(void* const* d_in, const int* in_sizes, int n_in,
                              void* d_out, int out_size, void* d_ws, size_t ws_size,
                              hipStream_t stream) {
  const float* query     = (const float*)d_in[0];
  const float* key       = (const float*)d_in[1];
  const float* value     = (const float*)d_in[2];
  const float* attn_bias = (const float*)d_in[3];
  const float* Wq        = (const float*)d_in[4];
  const float* bq        = (const float*)d_in[5];
  const float* Wk        = (const float*)d_in[6];
  const float* bk        = (const float*)d_in[7];

  float* out  = (float*)d_out;          // [16,1024,1024]
  float* attn = out + NBSD;             // [16,1024,1024]

  // ws carve: k, qm, valueT, attn_bf, MT+small all in ws.
  bf16* ws      = (bf16*)d_ws;
  bf16* k_hi    = ws;                   // split(key)
  bf16* k_lo    = ws + NBSD;
  bf16* qm_hi   = ws + 2 * NBSD;        // split(Q M)
  bf16* qm_lo   = ws + 3 * NBSD;
  bf16* valueT  = ws + 4 * NBSD;
  bf16* attn_bf = ws + 5 * NBSD;
  bf16* smallb  = ws + 6 * NBSD;
  bf16* MT_hi   = smallb;               // [1024,1024]
  bf16* MT_lo   = smallb + 1048576;
  float* fsm    = (float*)(smallb + 2097152);
  float* zeros  = fsm;                  // 1024
  float* w1     = fsm + 1024;           // 1024
  float* w2     = fsm + 2048;           // 1024
  float* cbuf   = fsm + 3072;           // 1
  float* v1     = fsm + 4096;           // 16384
  float* v2     = fsm + 20480;          // 16384
  float* w1p    = fsm + 36864;          // 8x1024
  float* w2p    = fsm + 45056;          // 8x1024
  // query splits live in d_out's `out` region (dead before PV writes out)
  bf16* q_hi = (bf16*)d_out;
  bf16* q_lo = q_hi + NBSD;

  // --- L3-locality-ordered pipeline ---
  // 1) tiny precompute: w1 = Wq^T bk, w2 = Wk^T bq, c, zeros
  wpart_kernel<<<65, 256, 0, stream>>>(Wq, Wk, bq, bk, w1p, w2p, cbuf, zeros);
  wreduce_kernel<<<8, 256, 0, stream>>>(w1p, w2p, w1, w2);

  // 2) conv-q (+v1 dot) — q splits land in d_out, L3-hot for QM
  split_convert_dot<<<4096, 256, 0, stream>>>(query, q_hi, q_lo, w1, v1);

  // 3) MT = (Wq^T Wk)^T (small; B operand for QM, written just before it)
  mt_split<<<dim3(16, 16), 256, 0, stream>>>(Wk, Wq, MT_hi, MT_lo);

  // 4) value transpose (moved BEFORE QM: keeps the QM->energy gap small)
  transpose_convert<<<dim3(32, 32, 16), 256, 0, stream>>>(value, valueT);

  // 5) QM = query @ M  (q splits ~108 MB old -> L3-hot; no pending dirty k)
  gemm32_split<0><<<256, 512, 0, stream>>>(q_hi, q_lo, 0, MT_hi, MT_lo, 0,
                                           zeros, qm_hi, qm_lo, nullptr, 0,
                                           nullptr, nullptr, nullptr);

  // 6) conv-k (+v2 dot) — k splits L3-hot for energy
  split_convert_dot<<<4096, 256, 0, stream>>>(key, k_hi, k_lo, w2, v2);

  // 7) energy = QM K^T + attn_bias + v1[s] + v2[t] + c
  gemm32_split<1><<<256, 512, 0, stream>>>(qm_hi, qm_lo, (long)S * D,
                                           k_hi, k_lo, (long)S * D,
                                           attn_bias, nullptr, nullptr, attn, (long)S * S,
                                           v1, v2, cbuf);

  // 8) softmax in place + bf16 copy
  softmax_rows<<<BATCH * S, 256, 0, stream>>>(attn, attn_bf);

  // 9) out = attention @ value
  gemm8_plain<<<256, 512, 0, stream>>>(attn_bf, (long)S * S, valueT, (long)D * S,
                                       out, (long)S * D);
}

// Round 13
// 440.687 us; speedup vs baseline: 1.0963x; 1.0792x over previous
//
#include <hip/hip_runtime.h>

// ---------------------------------------------------------------------------
// RVMixtureSynthesizers: q = query@Wq^T + bq ; k = key@Wk^T + bk
//   energy = q@k^T + attn_bias ; attention = softmax(energy) ; out = attention@value
// Outputs: out [16,1024,1024] fp32, attention [16,1024,1024] fp32 (concat in d_out)
//
// R12 = exact revert to R5 (measured best: 435.9 us, absmax 0.03125).
// Split GEMMs on mfma_f32_32x32x16_bf16, 3 phases/K-tile (hh, hl, lh):
// {reads; stage; counted vmcnt; barrier; lgkm(0); setprio 16 MFMA; barrier}.
// Split-bf16 (hh+hl+lh) for proj and QK^T; PV plain bf16 (R3 structure).
// ---------------------------------------------------------------------------

#define AS1 __attribute__((address_space(1)))
#define AS3 __attribute__((address_space(3)))
#define VMCNT(n) asm volatile("s_waitcnt vmcnt(" #n ")" ::: "memory")
#define LGKM(n)  asm volatile("s_waitcnt lgkmcnt(" #n ")" ::: "memory")
#define SBARRIER asm volatile("s_barrier" ::: "memory")
#define SB0 __builtin_amdgcn_sched_barrier(0)

typedef __bf16 bf16;
typedef __bf16 bf16x4 __attribute__((ext_vector_type(4)));
typedef __bf16 bf16x8 __attribute__((ext_vector_type(8)));
typedef float  f32x4  __attribute__((ext_vector_type(4)));
typedef float  f32x16 __attribute__((ext_vector_type(16)));

constexpr int BATCH = 16;
constexpr int S = 1024;
constexpr int D = 1024;
constexpr long NBSD = (long)BATCH * S * D;   // 16777216

constexpr int GBM = 256, GBN = 256, GBK = 32;
constexpr int NTK = 1024 / GBK;              // 32 K-tiles
constexpr int ARR = GBM * GBK;               // 8192 elems = 16 KB per array

__device__ __forceinline__ void stage16(const bf16* src, const bf16* dst) {
  __builtin_amdgcn_global_load_lds((const AS1 void*)src, (AS3 void*)dst, 16, 0, 0);
}

// ---------------------------------------------------------------------------
__global__ __launch_bounds__(256) void split_convert(
    const float* __restrict__ in, bf16* __restrict__ hi, bf16* __restrict__ lo, int n4) {
  int i = blockIdx.x * blockDim.x + threadIdx.x;
  int stride = gridDim.x * blockDim.x;
  for (; i < n4; i += stride) {
    f32x4 x = ((const f32x4*)in)[i];
    bf16x4 h, l;
#pragma unroll
    for (int j = 0; j < 4; ++j) {
      float v = x[j];
      bf16 hh = (bf16)v;
      h[j] = hh;
      l[j] = (bf16)(v - (float)hh);
    }
    ((bf16x4*)hi)[i] = h;
    ((bf16x4*)lo)[i] = l;
  }
}

// ---------------------------------------------------------------------------
__global__ __launch_bounds__(256) void transpose_convert(
    const float* __restrict__ v, bf16* __restrict__ vT) {
  __shared__ float tile[32][33];
  const int b = blockIdx.z;
  const int t0 = blockIdx.y * 32, d0 = blockIdx.x * 32;
  const int tx = threadIdx.x & 31, ty = threadIdx.x >> 5;
  const float* src = v + (long)b * S * D;
#pragma unroll
  for (int i = 0; i < 4; ++i)
    tile[ty + i * 8][tx] = src[(long)(t0 + ty + i * 8) * D + d0 + tx];
  __syncthreads();
  bf16* dst = vT + (long)b * D * S;
#pragma unroll
  for (int i = 0; i < 4; ++i)
    dst[(long)(d0 + ty + i * 8) * S + t0 + tx] = (bf16)tile[tx][ty + i * 8];
}

// ---------------------------------------------------------------------------
// Split-bf16 GEMM on mfma_f32_32x32x16_bf16. BM=BN=256, BK=32, 512 thr
// (8 waves 2x4, 128x64 out/wave = 4x2 frags of 32x32). LDS: 2 bufs x
// {Ah,Al,Bh,Bl} x 16KB = 128 KB. 3 phases/K-tile (hh, hl, lh), 16 MFMA each.
// vmcnt ledger (steady): P1 issues AhBh' -> queue 8, wait 6 (retires Bl(t));
// P2 issues Bl' -> wait 6 (retires Al(t)); P3 issues Al' -> wait 4 (retires
// Ah',Bh'). Never drains to 0 mid-loop.
template <int EPI>
__global__ __launch_bounds__(512, 2) void gemm32_split(
    const bf16* __restrict__ Ah_g, const bf16* __restrict__ Al_g, long a_bs,
    const bf16* __restrict__ Bh_g, const bf16* __restrict__ Bl_g, long b_bs,
    const float* __restrict__ bias,
    bf16* __restrict__ Ch, bf16* __restrict__ Cl,
    float* __restrict__ Cf, long c_bs) {
  __shared__ bf16 lds[2 * 4 * ARR];   // 128 KB

  const int tid = threadIdx.x;
  const int lane = tid & 63, wid = tid >> 6;
  const int wr = wid >> 2, wc = wid & 3;          // 2x4 wave grid
  const int lr = lane & 31;                       // row/col within 32-frag
  const int lk = lane >> 5;                       // k-half (0,1)

  // T1 bijective XCD swizzle (nwg=256)
  const int w = blockIdx.x;
  const int swz = (w & 7) * 32 + (w >> 3);
  int z, by, bx;
  if constexpr (EPI == 0) { z = 0; by = swz >> 2; bx = swz & 3; }
  else { z = swz >> 4; by = (swz >> 2) & 3; bx = swz & 3; }
  const long brow = (long)by * GBM, bcol = (long)bx * GBN;

  const bf16* A_h = Ah_g + (long)z * a_bs;
  const bf16* A_l = Al_g + (long)z * a_bs;
  const bf16* B_h = Bh_g + (long)z * b_bs;
  const bf16* B_l = Bl_g + (long)z * b_bs;

  const int srow = tid >> 2;                                  // 0..127
  const int csw = ((tid & 3) ^ ((srow >> 1) & 3)) * 8;        // source pre-swizzle
  const long asrc = (brow + srow) * 1024 + csw;
  const long bsrc = (bcol + srow) * 1024 + csw;
  const int dstoff = wid * 512;                               // wave-uniform base

  // fragment read offsets: row r in tile, k-slice s (K=16 each):
  //   chunk = 2*s + lk ; elem = r*32 + (chunk ^ ((r>>1)&3))*8
  int aoff[4][2], boff[2][2];
#pragma unroll
  for (int i = 0; i < 4; ++i) {
    const int r = wr * 128 + i * 32 + lr;
#pragma unroll
    for (int s = 0; s < 2; ++s)
      aoff[i][s] = r * 32 + (((2 * s + lk) ^ ((r >> 1) & 3)) * 8);
  }
#pragma unroll
  for (int j = 0; j < 2; ++j) {
    const int r = wc * 64 + j * 32 + lr;
#pragma unroll
    for (int s = 0; s < 2; ++s)
      boff[j][s] = r * 32 + (((2 * s + lk) ^ ((r >> 1) & 3)) * 8);
  }

  f32x16 acc[4][2] = {};
  bf16x8 ah[4][2], al[4][2], bh[2][2], bl[2][2];

#define STG(slot, arr, base, koff, rr) \
  stage16((base) + (koff) + (long)(rr) * 131072, \
          lds + ((slot) * 4 + (arr)) * ARR + (rr) * 4096 + dstoff)

#define CLUSTER(AF, BF) \
  __builtin_amdgcn_s_setprio(1); \
  _Pragma("unroll") \
  for (int s = 0; s < 2; ++s) \
    _Pragma("unroll") \
    for (int i = 0; i < 4; ++i) \
      _Pragma("unroll") \
      for (int j = 0; j < 2; ++j) \
        acc[i][j] = __builtin_amdgcn_mfma_f32_32x32x16_bf16(AF[i][s], BF[j][s], acc[i][j], 0, 0, 0); \
  __builtin_amdgcn_s_setprio(0)

  // ---- prologue: stage tile 0 (order Ah,Bh,Bl,Al); publish Ah,Bh
  STG(0, 0, A_h + asrc, 0, 0); STG(0, 0, A_h + asrc, 0, 1);
  STG(0, 2, B_h + bsrc, 0, 0); STG(0, 2, B_h + bsrc, 0, 1);
  STG(0, 3, B_l + bsrc, 0, 0); STG(0, 3, B_l + bsrc, 0, 1);
  STG(0, 1, A_l + asrc, 0, 0); STG(0, 1, A_l + asrc, 0, 1);
  VMCNT(4);          // Ah0,Bh0 retired; Bl0,Al0 in flight
  SBARRIER;

  for (int t = 0; t < NTK; ++t) {
    const int cur = t & 1, nxt = cur ^ 1;
    const long kn = (long)(t + 1) * GBK;
    const bool pf = (t + 1 < NTK);
    const bf16* lA_h = lds + (cur * 4 + 0) * ARR;
    const bf16* lA_l = lds + (cur * 4 + 1) * ARR;
    const bf16* lB_h = lds + (cur * 4 + 2) * ARR;
    const bf16* lB_l = lds + (cur * 4 + 3) * ARR;

    // ---- P1: read ah,bh | stage Ah',Bh' | vmcnt(6) | bar | lgkm0 | hh
#pragma unroll
    for (int i = 0; i < 4; ++i)
#pragma unroll
      for (int s = 0; s < 2; ++s) ah[i][s] = *(const bf16x8*)&lA_h[aoff[i][s]];
#pragma unroll
    for (int j = 0; j < 2; ++j)
#pragma unroll
      for (int s = 0; s < 2; ++s) bh[j][s] = *(const bf16x8*)&lB_h[boff[j][s]];
    if (pf) {
      STG(nxt, 0, A_h + asrc, kn, 0); STG(nxt, 0, A_h + asrc, kn, 1);
      STG(nxt, 2, B_h + bsrc, kn, 0); STG(nxt, 2, B_h + bsrc, kn, 1);
      VMCNT(6);      // retires Bl(t)
    } else {
      VMCNT(2);      // tail: retires Bl(t), Al(t) still in flight
    }
    SBARRIER; LGKM(0); SB0;
    CLUSTER(ah, bh);
    SBARRIER;

    // ---- P2: read bl | stage Bl' | vmcnt(6) | bar | lgkm0 | hl
#pragma unroll
    for (int j = 0; j < 2; ++j)
#pragma unroll
      for (int s = 0; s < 2; ++s) bl[j][s] = *(const bf16x8*)&lB_l[boff[j][s]];
    if (pf) {
      STG(nxt, 3, B_l + bsrc, kn, 0); STG(nxt, 3, B_l + bsrc, kn, 1);
      VMCNT(6);      // retires Al(t)
    } else {
      VMCNT(0);      // tail: retires Al(t)
    }
    SBARRIER; LGKM(0); SB0;
    CLUSTER(ah, bl);
    SBARRIER;

    // ---- P3: read al | stage Al' | vmcnt(4) | bar | lgkm0 | lh
#pragma unroll
    for (int i = 0; i < 4; ++i)
#pragma unroll
      for (int s = 0; s < 2; ++s) al[i][s] = *(const bf16x8*)&lA_l[aoff[i][s]];
    if (pf) {
      STG(nxt, 1, A_l + asrc, kn, 0); STG(nxt, 1, A_l + asrc, kn, 1);
      VMCNT(4);      // retires Ah',Bh' (visible for P1(t+1))
    }
    SBARRIER; LGKM(0); SB0;
    CLUSTER(al, bh);
    SBARRIER;
  }
#undef STG
#undef CLUSTER

  // Epilogue. 32x32 C/D frag [m74/m101]: col = lane&31,
  // row = (reg&3) + 8*(reg>>2) + 4*(lane>>5)
  if constexpr (EPI == 0) {
#pragma unroll
    for (int j = 0; j < 2; ++j) {
      const long col = bcol + wc * 64 + j * 32 + lr;
      const float bv = bias[col];
#pragma unroll
      for (int i = 0; i < 4; ++i) {
        const long row0 = brow + wr * 128 + i * 32 + 4 * lk;
#pragma unroll
        for (int r = 0; r < 16; ++r) {
          const long row = row0 + (r & 3) + 8 * (r >> 2);
          const float c = acc[i][j][r] + bv;
          const bf16 h = (bf16)c;
          const bf16 l = (bf16)(c - (float)h);
          const long idx = row * 1024 + col;
          Ch[idx] = h;
          Cl[idx] = l;
        }
      }
    }
  } else {
    float* Cz = Cf + (long)z * c_bs;
#pragma unroll
    for (int j = 0; j < 2; ++j) {
      const long col = bcol + wc * 64 + j * 32 + lr;
#pragma unroll
      for (int i = 0; i < 4; ++i) {
        const long row0 = brow + wr * 128 + i * 32 + 4 * lk;
#pragma unroll
        for (int r = 0; r < 16; ++r) {
          const long row = row0 + (r & 3) + 8 * (r >> 2);
          Cz[row * 1024 + col] = acc[i][j][r] + bias[row * 1024 + col];
        }
      }
    }
  }
}

// ---------------------------------------------------------------------------
// Plain bf16 GEMM (PV), R3 structure: 2 bufs x {A,B} = 64KB; per K-tile
// stage t+1 ; vmcnt(4) ; barrier ; 12 reads + 32 MFMA ; barrier.
__global__ __launch_bounds__(512, 2) void gemm8_plain(
    const bf16* __restrict__ A_g, long a_bs,
    const bf16* __restrict__ B_g, long b_bs,
    float* __restrict__ C, long c_bs) {
  __shared__ bf16 lds[2 * 2 * ARR];   // 64 KB

  const int tid = threadIdx.x;
  const int lane = tid & 63, wid = tid >> 6;
  const int wr = wid >> 2, wc = wid & 3;
  const int fr = lane & 15, fq = lane >> 4;
  const int fsw = (fr >> 1) & 3;

  const int w = blockIdx.x;
  const int swz = (w & 7) * 32 + (w >> 3);
  const int z = swz >> 4, by = (swz >> 2) & 3, bx = swz & 3;
  const long brow = (long)by * GBM, bcol = (long)bx * GBN;

  const bf16* A = A_g + (long)z * a_bs;
  const bf16* B = B_g + (long)z * b_bs;

  const int srow = tid >> 2;
  const int csw = ((tid & 3) ^ ((srow >> 1) & 3)) * 8;
  const long asrc = (brow + srow) * 1024 + csw;
  const long bsrc = (bcol + srow) * 1024 + csw;
  const int dstoff = wid * 512;

  const int aoffb = (wr * 128 + fr) * 32 + (fq ^ fsw) * 8;
  const int boffb = (wc * 64 + fr) * 32 + (fq ^ fsw) * 8;

  f32x4 acc[8][4] = {};

#define STG2(slot, arr, base, koff, rr) \
  stage16((base) + (koff) + (long)(rr) * 131072, \
          lds + ((slot) * 2 + (arr)) * ARR + (rr) * 4096 + dstoff)

  STG2(0, 0, A + asrc, 0, 0); STG2(0, 0, A + asrc, 0, 1);
  STG2(0, 1, B + bsrc, 0, 0); STG2(0, 1, B + bsrc, 0, 1);

  for (int t = 0; t < NTK; ++t) {
    const int cur = t & 1, nxt = cur ^ 1;
    const bf16* lA = lds + (cur * 2 + 0) * ARR;
    const bf16* lB = lds + (cur * 2 + 1) * ARR;

    if (t + 1 < NTK) {
      const long kn = (long)(t + 1) * GBK;
      STG2(nxt, 0, A + asrc, kn, 0); STG2(nxt, 0, A + asrc, kn, 1);
      STG2(nxt, 1, B + bsrc, kn, 0); STG2(nxt, 1, B + bsrc, kn, 1);
      VMCNT(4);
    } else {
      VMCNT(0);
    }
    SB0;
    SBARRIER;

    bf16x8 ah[8], bh[4];
#pragma unroll
    for (int m = 0; m < 8; ++m) ah[m] = *(const bf16x8*)&lA[aoffb + m * 512];
#pragma unroll
    for (int n = 0; n < 4; ++n) bh[n] = *(const bf16x8*)&lB[boffb + n * 512];
#pragma unroll
    for (int n = 0; n < 4; ++n)
#pragma unroll
      for (int m = 0; m < 8; ++m)
        acc[m][n] = __builtin_amdgcn_mfma_f32_16x16x32_bf16(ah[m], bh[n], acc[m][n], 0, 0, 0);

    SBARRIER;
  }
#undef STG2

  float* Cz = C + (long)z * c_bs;
#pragma unroll
  for (int n = 0; n < 4; ++n) {
    const long col = bcol + wc * 64 + n * 16 + fr;
#pragma unroll
    for (int m = 0; m < 8; ++m) {
      const long row0 = brow + wr * 128 + m * 16 + fq * 4;
#pragma unroll
      for (int j = 0; j < 4; ++j)
        Cz[(row0 + j) * 1024 + col] = acc[m][n][j];
    }
  }
}

// ---------------------------------------------------------------------------
__global__ __launch_bounds__(256) void softmax_rows(
    float* __restrict__ attn, bf16* __restrict__ attn_bf) {
  const long row = blockIdx.x;
  float* p = attn + row * 1024;
  const int tid = threadIdx.x, lane = tid & 63, wid = tid >> 6;

  f32x4 x = ((const f32x4*)p)[tid];
  float m = fmaxf(fmaxf(x[0], x[1]), fmaxf(x[2], x[3]));
#pragma unroll
  for (int off = 32; off; off >>= 1) m = fmaxf(m, __shfl_xor(m, off));
  __shared__ float redm[4];
  if (lane == 0) redm[wid] = m;
  __syncthreads();
  m = fmaxf(fmaxf(redm[0], redm[1]), fmaxf(redm[2], redm[3]));

  f32x4 e;
#pragma unroll
  for (int j = 0; j < 4; ++j) e[j] = __expf(x[j] - m);
  float s = e[0] + e[1] + e[2] + e[3];
#pragma unroll
  for (int off = 32; off; off >>= 1) s += __shfl_xor(s, off);
  __shared__ float reds[4];
  if (lane == 0) reds[wid] = s;
  __syncthreads();
  s = reds[0] + reds[1] + reds[2] + reds[3];

  const float inv = 1.0f / s;
  f32x4 r;
  bf16x4 rb;
#pragma unroll
  for (int j = 0; j < 4; ++j) {
    r[j] = e[j] * inv;
    rb[j] = (bf16)r[j];
  }
  ((f32x4*)p)[tid] = r;
  ((bf16x4*)(attn_bf + row * 1024))[tid] = rb;
}

// ---------------------------------------------------------------------------
extern "C" void kernel_launch(void* const* d_in, const int* in_sizes, int n_in,
                              void* d_out, int out_size, void* d_ws, size_t ws_size,
                              hipStream_t stream) {
  const float* query     = (const float*)d_in[0];
  const float* key       = (const float*)d_in[1];
  const float* value     = (const float*)d_in[2];
  const float* attn_bias = (const float*)d_in[3];
  const float* Wq        = (const float*)d_in[4];
  const float* bq        = (const float*)d_in[5];
  const float* Wk        = (const float*)d_in[6];
  const float* bk        = (const float*)d_in[7];

  float* out  = (float*)d_out;          // [16,1024,1024]
  float* attn = out + NBSD;             // [16,1024,1024]

  // ws carve (bf16 elements). Total = 6*NBSD + 4*D*D = 200 MiB.
  bf16* ws    = (bf16*)d_ws;
  bf16* q_hi  = ws;
  bf16* q_lo  = ws + NBSD;
  bf16* k_hi  = ws + 2 * NBSD;
  bf16* k_lo  = ws + 3 * NBSD;
  bf16* Wq_hi = ws + 4 * NBSD;
  bf16* Wq_lo = Wq_hi + (long)D * D;
  bf16* Wk_hi = Wq_lo + (long)D * D;
  bf16* Wk_lo = Wk_hi + (long)D * D;
  bf16* scr   = Wk_lo + (long)D * D;    // 2*NBSD scratch
  bf16* key_hi = scr;
  bf16* key_lo = scr + NBSD;
  bf16* valueT  = scr;                  // reused after key splits die
  bf16* attn_bf = scr + NBSD;
  bf16* query_hi = (bf16*)d_out;        // lives in `out` region until PV
  bf16* query_lo = query_hi + NBSD;

  // 1) split conversions
  split_convert<<<2048, 256, 0, stream>>>(query, query_hi, query_lo, (int)(NBSD / 4));
  split_convert<<<2048, 256, 0, stream>>>(key, key_hi, key_lo, (int)(NBSD / 4));
  split_convert<<<512, 256, 0, stream>>>(Wq, Wq_hi, Wq_lo, D * D / 4);
  split_convert<<<512, 256, 0, stream>>>(Wk, Wk_hi, Wk_lo, D * D / 4);

  // 2) projections: [16384,1024] x [1024,1024]^T (grid 64x4 = 256 blocks)
  gemm32_split<0><<<256, 512, 0, stream>>>(query_hi, query_lo, 0, Wq_hi, Wq_lo, 0,
                                           bq, q_hi, q_lo, nullptr, 0);
  gemm32_split<0><<<256, 512, 0, stream>>>(key_hi, key_lo, 0, Wk_hi, Wk_lo, 0,
                                           bk, k_hi, k_lo, nullptr, 0);

  // 3) value transpose (key splits now dead)
  transpose_convert<<<dim3(32, 32, 16), 256, 0, stream>>>(value, valueT);

  // 4) energy = q k^T + bias (grid 16 z x 4x4 = 256 blocks)
  gemm32_split<1><<<256, 512, 0, stream>>>(q_hi, q_lo, (long)S * D, k_hi, k_lo, (long)S * D,
                                           attn_bias, nullptr, nullptr, attn, (long)S * S);

  // 5) softmax in place + bf16 copy
  softmax_rows<<<BATCH * S, 256, 0, stream>>>(attn, attn_bf);

  // 6) out = attention @ value
  gemm8_plain<<<256, 512, 0, stream>>>(attn_bf, (long)S * S, valueT, (long)D * S,
                                       out, (long)S * D);
}

// Round 14
// 433.911 us; speedup vs baseline: 1.1134x; 1.0156x over previous
//
#include <hip/hip_runtime.h>

// ---------------------------------------------------------------------------
// RVMixtureSynthesizers: q = query@Wq^T + bq ; k = key@Wk^T + bk
//   energy = q@k^T + attn_bias ; attention = softmax(energy) ; out = attention@value
// Outputs: out [16,1024,1024] fp32, attention [16,1024,1024] fp32 (concat in d_out)
//
// R13 = R12 (the measured-best R5 pipeline) + PV ported to 32x32 MFMA using
// the same verified fragment/epilogue machinery as gemm32_split and the same
// verified sync skeleton as gemm8_plain (1 phase/K-tile, counted vmcnt(4)).
// Split-bf16 (hh+hl+lh) for proj and QK^T; PV plain bf16.
// ---------------------------------------------------------------------------

#define AS1 __attribute__((address_space(1)))
#define AS3 __attribute__((address_space(3)))
#define VMCNT(n) asm volatile("s_waitcnt vmcnt(" #n ")" ::: "memory")
#define LGKM(n)  asm volatile("s_waitcnt lgkmcnt(" #n ")" ::: "memory")
#define SBARRIER asm volatile("s_barrier" ::: "memory")
#define SB0 __builtin_amdgcn_sched_barrier(0)

typedef __bf16 bf16;
typedef __bf16 bf16x4 __attribute__((ext_vector_type(4)));
typedef __bf16 bf16x8 __attribute__((ext_vector_type(8)));
typedef float  f32x4  __attribute__((ext_vector_type(4)));
typedef float  f32x16 __attribute__((ext_vector_type(16)));

constexpr int BATCH = 16;
constexpr int S = 1024;
constexpr int D = 1024;
constexpr long NBSD = (long)BATCH * S * D;   // 16777216

constexpr int GBM = 256, GBN = 256, GBK = 32;
constexpr int NTK = 1024 / GBK;              // 32 K-tiles
constexpr int ARR = GBM * GBK;               // 8192 elems = 16 KB per array

__device__ __forceinline__ void stage16(const bf16* src, const bf16* dst) {
  __builtin_amdgcn_global_load_lds((const AS1 void*)src, (AS3 void*)dst, 16, 0, 0);
}

// ---------------------------------------------------------------------------
__global__ __launch_bounds__(256) void split_convert(
    const float* __restrict__ in, bf16* __restrict__ hi, bf16* __restrict__ lo, int n4) {
  int i = blockIdx.x * blockDim.x + threadIdx.x;
  int stride = gridDim.x * blockDim.x;
  for (; i < n4; i += stride) {
    f32x4 x = ((const f32x4*)in)[i];
    bf16x4 h, l;
#pragma unroll
    for (int j = 0; j < 4; ++j) {
      float v = x[j];
      bf16 hh = (bf16)v;
      h[j] = hh;
      l[j] = (bf16)(v - (float)hh);
    }
    ((bf16x4*)hi)[i] = h;
    ((bf16x4*)lo)[i] = l;
  }
}

// ---------------------------------------------------------------------------
__global__ __launch_bounds__(256) void transpose_convert(
    const float* __restrict__ v, bf16* __restrict__ vT) {
  __shared__ float tile[32][33];
  const int b = blockIdx.z;
  const int t0 = blockIdx.y * 32, d0 = blockIdx.x * 32;
  const int tx = threadIdx.x & 31, ty = threadIdx.x >> 5;
  const float* src = v + (long)b * S * D;
#pragma unroll
  for (int i = 0; i < 4; ++i)
    tile[ty + i * 8][tx] = src[(long)(t0 + ty + i * 8) * D + d0 + tx];
  __syncthreads();
  bf16* dst = vT + (long)b * D * S;
#pragma unroll
  for (int i = 0; i < 4; ++i)
    dst[(long)(d0 + ty + i * 8) * S + t0 + tx] = (bf16)tile[tx][ty + i * 8];
}

// ---------------------------------------------------------------------------
// Split-bf16 GEMM on mfma_f32_32x32x16_bf16 (verbatim R5/R12). BM=BN=256,
// BK=32, 512 thr (8 waves 2x4, 128x64/wave = 4x2 frags of 32x32).
// LDS: 2 bufs x {Ah,Al,Bh,Bl} x 16KB = 128 KB. 3 phases/K-tile (hh, hl, lh).
// vmcnt ledger (steady): P1 w6 / P2 w6 / P3 w4. Never drains mid-loop.
template <int EPI>
__global__ __launch_bounds__(512, 2) void gemm32_split(
    const bf16* __restrict__ Ah_g, const bf16* __restrict__ Al_g, long a_bs,
    const bf16* __restrict__ Bh_g, const bf16* __restrict__ Bl_g, long b_bs,
    const float* __restrict__ bias,
    bf16* __restrict__ Ch, bf16* __restrict__ Cl,
    float* __restrict__ Cf, long c_bs) {
  __shared__ bf16 lds[2 * 4 * ARR];   // 128 KB

  const int tid = threadIdx.x;
  const int lane = tid & 63, wid = tid >> 6;
  const int wr = wid >> 2, wc = wid & 3;          // 2x4 wave grid
  const int lr = lane & 31;                       // row/col within 32-frag
  const int lk = lane >> 5;                       // k-half (0,1)

  // T1 bijective XCD swizzle (nwg=256)
  const int w = blockIdx.x;
  const int swz = (w & 7) * 32 + (w >> 3);
  int z, by, bx;
  if constexpr (EPI == 0) { z = 0; by = swz >> 2; bx = swz & 3; }
  else { z = swz >> 4; by = (swz >> 2) & 3; bx = swz & 3; }
  const long brow = (long)by * GBM, bcol = (long)bx * GBN;

  const bf16* A_h = Ah_g + (long)z * a_bs;
  const bf16* A_l = Al_g + (long)z * a_bs;
  const bf16* B_h = Bh_g + (long)z * b_bs;
  const bf16* B_l = Bl_g + (long)z * b_bs;

  const int srow = tid >> 2;                                  // 0..127
  const int csw = ((tid & 3) ^ ((srow >> 1) & 3)) * 8;        // source pre-swizzle
  const long asrc = (brow + srow) * 1024 + csw;
  const long bsrc = (bcol + srow) * 1024 + csw;
  const int dstoff = wid * 512;                               // wave-uniform base

  // fragment read offsets: row r in tile, k-slice s (K=16 each):
  //   chunk = 2*s + lk ; elem = r*32 + (chunk ^ ((r>>1)&3))*8
  int aoff[4][2], boff[2][2];
#pragma unroll
  for (int i = 0; i < 4; ++i) {
    const int r = wr * 128 + i * 32 + lr;
#pragma unroll
    for (int s = 0; s < 2; ++s)
      aoff[i][s] = r * 32 + (((2 * s + lk) ^ ((r >> 1) & 3)) * 8);
  }
#pragma unroll
  for (int j = 0; j < 2; ++j) {
    const int r = wc * 64 + j * 32 + lr;
#pragma unroll
    for (int s = 0; s < 2; ++s)
      boff[j][s] = r * 32 + (((2 * s + lk) ^ ((r >> 1) & 3)) * 8);
  }

  f32x16 acc[4][2] = {};
  bf16x8 ah[4][2], al[4][2], bh[2][2], bl[2][2];

#define STG(slot, arr, base, koff, rr) \
  stage16((base) + (koff) + (long)(rr) * 131072, \
          lds + ((slot) * 4 + (arr)) * ARR + (rr) * 4096 + dstoff)

#define CLUSTER(AF, BF) \
  __builtin_amdgcn_s_setprio(1); \
  _Pragma("unroll") \
  for (int s = 0; s < 2; ++s) \
    _Pragma("unroll") \
    for (int i = 0; i < 4; ++i) \
      _Pragma("unroll") \
      for (int j = 0; j < 2; ++j) \
        acc[i][j] = __builtin_amdgcn_mfma_f32_32x32x16_bf16(AF[i][s], BF[j][s], acc[i][j], 0, 0, 0); \
  __builtin_amdgcn_s_setprio(0)

  // ---- prologue: stage tile 0 (order Ah,Bh,Bl,Al); publish Ah,Bh
  STG(0, 0, A_h + asrc, 0, 0); STG(0, 0, A_h + asrc, 0, 1);
  STG(0, 2, B_h + bsrc, 0, 0); STG(0, 2, B_h + bsrc, 0, 1);
  STG(0, 3, B_l + bsrc, 0, 0); STG(0, 3, B_l + bsrc, 0, 1);
  STG(0, 1, A_l + asrc, 0, 0); STG(0, 1, A_l + asrc, 0, 1);
  VMCNT(4);          // Ah0,Bh0 retired; Bl0,Al0 in flight
  SBARRIER;

  for (int t = 0; t < NTK; ++t) {
    const int cur = t & 1, nxt = cur ^ 1;
    const long kn = (long)(t + 1) * GBK;
    const bool pf = (t + 1 < NTK);
    const bf16* lA_h = lds + (cur * 4 + 0) * ARR;
    const bf16* lA_l = lds + (cur * 4 + 1) * ARR;
    const bf16* lB_h = lds + (cur * 4 + 2) * ARR;
    const bf16* lB_l = lds + (cur * 4 + 3) * ARR;

    // ---- P1: read ah,bh | stage Ah',Bh' | vmcnt(6) | bar | lgkm0 | hh
#pragma unroll
    for (int i = 0; i < 4; ++i)
#pragma unroll
      for (int s = 0; s < 2; ++s) ah[i][s] = *(const bf16x8*)&lA_h[aoff[i][s]];
#pragma unroll
    for (int j = 0; j < 2; ++j)
#pragma unroll
      for (int s = 0; s < 2; ++s) bh[j][s] = *(const bf16x8*)&lB_h[boff[j][s]];
    if (pf) {
      STG(nxt, 0, A_h + asrc, kn, 0); STG(nxt, 0, A_h + asrc, kn, 1);
      STG(nxt, 2, B_h + bsrc, kn, 0); STG(nxt, 2, B_h + bsrc, kn, 1);
      VMCNT(6);      // retires Bl(t)
    } else {
      VMCNT(2);      // tail: retires Bl(t), Al(t) still in flight
    }
    SBARRIER; LGKM(0); SB0;
    CLUSTER(ah, bh);
    SBARRIER;

    // ---- P2: read bl | stage Bl' | vmcnt(6) | bar | lgkm0 | hl
#pragma unroll
    for (int j = 0; j < 2; ++j)
#pragma unroll
      for (int s = 0; s < 2; ++s) bl[j][s] = *(const bf16x8*)&lB_l[boff[j][s]];
    if (pf) {
      STG(nxt, 3, B_l + bsrc, kn, 0); STG(nxt, 3, B_l + bsrc, kn, 1);
      VMCNT(6);      // retires Al(t)
    } else {
      VMCNT(0);      // tail: retires Al(t)
    }
    SBARRIER; LGKM(0); SB0;
    CLUSTER(ah, bl);
    SBARRIER;

    // ---- P3: read al | stage Al' | vmcnt(4) | bar | lgkm0 | lh
#pragma unroll
    for (int i = 0; i < 4; ++i)
#pragma unroll
      for (int s = 0; s < 2; ++s) al[i][s] = *(const bf16x8*)&lA_l[aoff[i][s]];
    if (pf) {
      STG(nxt, 1, A_l + asrc, kn, 0); STG(nxt, 1, A_l + asrc, kn, 1);
      VMCNT(4);      // retires Ah',Bh' (visible for P1(t+1))
    }
    SBARRIER; LGKM(0); SB0;
    CLUSTER(al, bh);
    SBARRIER;
  }
#undef STG
#undef CLUSTER

  // Epilogue. 32x32 C/D frag [m74/m101]: col = lane&31,
  // row = (reg&3) + 8*(reg>>2) + 4*(lane>>5)
  if constexpr (EPI == 0) {
#pragma unroll
    for (int j = 0; j < 2; ++j) {
      const long col = bcol + wc * 64 + j * 32 + lr;
      const float bv = bias[col];
#pragma unroll
      for (int i = 0; i < 4; ++i) {
        const long row0 = brow + wr * 128 + i * 32 + 4 * lk;
#pragma unroll
        for (int r = 0; r < 16; ++r) {
          const long row = row0 + (r & 3) + 8 * (r >> 2);
          const float c = acc[i][j][r] + bv;
          const bf16 h = (bf16)c;
          const bf16 l = (bf16)(c - (float)h);
          const long idx = row * 1024 + col;
          Ch[idx] = h;
          Cl[idx] = l;
        }
      }
    }
  } else {
    float* Cz = Cf + (long)z * c_bs;
#pragma unroll
    for (int j = 0; j < 2; ++j) {
      const long col = bcol + wc * 64 + j * 32 + lr;
#pragma unroll
      for (int i = 0; i < 4; ++i) {
        const long row0 = brow + wr * 128 + i * 32 + 4 * lk;
#pragma unroll
        for (int r = 0; r < 16; ++r) {
          const long row = row0 + (r & 3) + 8 * (r >> 2);
          Cz[row * 1024 + col] = acc[i][j][r] + bias[row * 1024 + col];
        }
      }
    }
  }
}

// ---------------------------------------------------------------------------
// Plain bf16 GEMM (PV) on mfma_f32_32x32x16_bf16. Same fragment machinery as
// gemm32_split; same sync skeleton as the R3 gemm8_plain (1 phase/K-tile):
//   stage(t+1) 4 DMA ; VMCNT(4) (retires tile t) ; barrier ; 12 ds_read_b128 ;
//   LGKM(0) ; setprio 16 MFMA ; barrier.
// LDS: 2 bufs x {A,B} x 16KB = 64 KB.
__global__ __launch_bounds__(512, 2) void gemm32_plain(
    const bf16* __restrict__ A_g, long a_bs,
    const bf16* __restrict__ B_g, long b_bs,
    float* __restrict__ C, long c_bs) {
  __shared__ bf16 lds[2 * 2 * ARR];   // 64 KB

  const int tid = threadIdx.x;
  const int lane = tid & 63, wid = tid >> 6;
  const int wr = wid >> 2, wc = wid & 3;          // 2x4 wave grid
  const int lr = lane & 31;
  const int lk = lane >> 5;

  const int w = blockIdx.x;
  const int swz = (w & 7) * 32 + (w >> 3);
  const int z = swz >> 4, by = (swz >> 2) & 3, bx = swz & 3;
  const long brow = (long)by * GBM, bcol = (long)bx * GBN;

  const bf16* A = A_g + (long)z * a_bs;
  const bf16* B = B_g + (long)z * b_bs;

  const int srow = tid >> 2;
  const int csw = ((tid & 3) ^ ((srow >> 1) & 3)) * 8;
  const long asrc = (brow + srow) * 1024 + csw;
  const long bsrc = (bcol + srow) * 1024 + csw;
  const int dstoff = wid * 512;

  int aoff[4][2], boff[2][2];
#pragma unroll
  for (int i = 0; i < 4; ++i) {
    const int r = wr * 128 + i * 32 + lr;
#pragma unroll
    for (int s = 0; s < 2; ++s)
      aoff[i][s] = r * 32 + (((2 * s + lk) ^ ((r >> 1) & 3)) * 8);
  }
#pragma unroll
  for (int j = 0; j < 2; ++j) {
    const int r = wc * 64 + j * 32 + lr;
#pragma unroll
    for (int s = 0; s < 2; ++s)
      boff[j][s] = r * 32 + (((2 * s + lk) ^ ((r >> 1) & 3)) * 8);
  }

  f32x16 acc[4][2] = {};
  bf16x8 af[4][2], bf_[2][2];

#define STG2(slot, arr, base, koff, rr) \
  stage16((base) + (koff) + (long)(rr) * 131072, \
          lds + ((slot) * 2 + (arr)) * ARR + (rr) * 4096 + dstoff)

  // prologue: stage tile 0
  STG2(0, 0, A + asrc, 0, 0); STG2(0, 0, A + asrc, 0, 1);
  STG2(0, 1, B + bsrc, 0, 0); STG2(0, 1, B + bsrc, 0, 1);

  for (int t = 0; t < NTK; ++t) {
    const int cur = t & 1, nxt = cur ^ 1;
    const bf16* lA = lds + (cur * 2 + 0) * ARR;
    const bf16* lB = lds + (cur * 2 + 1) * ARR;

    if (t + 1 < NTK) {
      const long kn = (long)(t + 1) * GBK;
      STG2(nxt, 0, A + asrc, kn, 0); STG2(nxt, 0, A + asrc, kn, 1);
      STG2(nxt, 1, B + bsrc, kn, 0); STG2(nxt, 1, B + bsrc, kn, 1);
      VMCNT(4);      // retires tile t (the 4 just-issued stay in flight)
    } else {
      VMCNT(0);
    }
    SB0;
    SBARRIER;

#pragma unroll
    for (int i = 0; i < 4; ++i)
#pragma unroll
      for (int s = 0; s < 2; ++s) af[i][s] = *(const bf16x8*)&lA[aoff[i][s]];
#pragma unroll
    for (int j = 0; j < 2; ++j)
#pragma unroll
      for (int s = 0; s < 2; ++s) bf_[j][s] = *(const bf16x8*)&lB[boff[j][s]];
    LGKM(0); SB0;
    __builtin_amdgcn_s_setprio(1);
#pragma unroll
    for (int s = 0; s < 2; ++s)
#pragma unroll
      for (int i = 0; i < 4; ++i)
#pragma unroll
        for (int j = 0; j < 2; ++j)
          acc[i][j] = __builtin_amdgcn_mfma_f32_32x32x16_bf16(af[i][s], bf_[j][s], acc[i][j], 0, 0, 0);
    __builtin_amdgcn_s_setprio(0);

    SBARRIER;
  }
#undef STG2

  float* Cz = C + (long)z * c_bs;
#pragma unroll
  for (int j = 0; j < 2; ++j) {
    const long col = bcol + wc * 64 + j * 32 + lr;
#pragma unroll
    for (int i = 0; i < 4; ++i) {
      const long row0 = brow + wr * 128 + i * 32 + 4 * lk;
#pragma unroll
      for (int r = 0; r < 16; ++r) {
        const long row = row0 + (r & 3) + 8 * (r >> 2);
        Cz[row * 1024 + col] = acc[i][j][r];
      }
    }
  }
}

// ---------------------------------------------------------------------------
__global__ __launch_bounds__(256) void softmax_rows(
    float* __restrict__ attn, bf16* __restrict__ attn_bf) {
  const long row = blockIdx.x;
  float* p = attn + row * 1024;
  const int tid = threadIdx.x, lane = tid & 63, wid = tid >> 6;

  f32x4 x = ((const f32x4*)p)[tid];
  float m = fmaxf(fmaxf(x[0], x[1]), fmaxf(x[2], x[3]));
#pragma unroll
  for (int off = 32; off; off >>= 1) m = fmaxf(m, __shfl_xor(m, off));
  __shared__ float redm[4];
  if (lane == 0) redm[wid] = m;
  __syncthreads();
  m = fmaxf(fmaxf(redm[0], redm[1]), fmaxf(redm[2], redm[3]));

  f32x4 e;
#pragma unroll
  for (int j = 0; j < 4; ++j) e[j] = __expf(x[j] - m);
  float s = e[0] + e[1] + e[2] + e[3];
#pragma unroll
  for (int off = 32; off; off >>= 1) s += __shfl_xor(s, off);
  __shared__ float reds[4];
  if (lane == 0) reds[wid] = s;
  __syncthreads();
  s = reds[0] + reds[1] + reds[2] + reds[3];

  const float inv = 1.0f / s;
  f32x4 r;
  bf16x4 rb;
#pragma unroll
  for (int j = 0; j < 4; ++j) {
    r[j] = e[j] * inv;
    rb[j] = (bf16)r[j];
  }
  ((f32x4*)p)[tid] = r;
  ((bf16x4*)(attn_bf + row * 1024))[tid] = rb;
}

// ---------------------------------------------------------------------------
extern "C" void kernel_launch(void* const* d_in, const int* in_sizes, int n_in,
                              void* d_out, int out_size, void* d_ws, size_t ws_size,
                              hipStream_t stream) {
  const float* query     = (const float*)d_in[0];
  const float* key       = (const float*)d_in[1];
  const float* value     = (const float*)d_in[2];
  const float* attn_bias = (const float*)d_in[3];
  const float* Wq        = (const float*)d_in[4];
  const float* bq        = (const float*)d_in[5];
  const float* Wk        = (const float*)d_in[6];
  const float* bk        = (const float*)d_in[7];

  float* out  = (float*)d_out;          // [16,1024,1024]
  float* attn = out + NBSD;             // [16,1024,1024]

  // ws carve (bf16 elements). Total = 6*NBSD + 4*D*D = 200 MiB.
  bf16* ws    = (bf16*)d_ws;
  bf16* q_hi  = ws;
  bf16* q_lo  = ws + NBSD;
  bf16* k_hi  = ws + 2 * NBSD;
  bf16* k_lo  = ws + 3 * NBSD;
  bf16* Wq_hi = ws + 4 * NBSD;
  bf16* Wq_lo = Wq_hi + (long)D * D;
  bf16* Wk_hi = Wq_lo + (long)D * D;
  bf16* Wk_lo = Wk_hi + (long)D * D;
  bf16* scr   = Wk_lo + (long)D * D;    // 2*NBSD scratch
  bf16* key_hi = scr;
  bf16* key_lo = scr + NBSD;
  bf16* valueT  = scr;                  // reused after key splits die
  bf16* attn_bf = scr + NBSD;
  bf16* query_hi = (bf16*)d_out;        // lives in `out` region until PV
  bf16* query_lo = query_hi + NBSD;

  // 1) split conversions
  split_convert<<<2048, 256, 0, stream>>>(query, query_hi, query_lo, (int)(NBSD / 4));
  split_convert<<<2048, 256, 0, stream>>>(key, key_hi, key_lo, (int)(NBSD / 4));
  split_convert<<<512, 256, 0, stream>>>(Wq, Wq_hi, Wq_lo, D * D / 4);
  split_convert<<<512, 256, 0, stream>>>(Wk, Wk_hi, Wk_lo, D * D / 4);

  // 2) projections: [16384,1024] x [1024,1024]^T (grid 64x4 = 256 blocks)
  gemm32_split<0><<<256, 512, 0, stream>>>(query_hi, query_lo, 0, Wq_hi, Wq_lo, 0,
                                           bq, q_hi, q_lo, nullptr, 0);
  gemm32_split<0><<<256, 512, 0, stream>>>(key_hi, key_lo, 0, Wk_hi, Wk_lo, 0,
                                           bk, k_hi, k_lo, nullptr, 0);

  // 3) value transpose (key splits now dead)
  transpose_convert<<<dim3(32, 32, 16), 256, 0, stream>>>(value, valueT);

  // 4) energy = q k^T + bias (grid 16 z x 4x4 = 256 blocks)
  gemm32_split<1><<<256, 512, 0, stream>>>(q_hi, q_lo, (long)S * D, k_hi, k_lo, (long)S * D,
                                           attn_bias, nullptr, nullptr, attn, (long)S * S);

  // 5) softmax in place + bf16 copy
  softmax_rows<<<BATCH * S, 256, 0, stream>>>(attn, attn_bf);

  // 6) out = attention @ value (32x32 MFMA)
  gemm32_plain<<<256, 512, 0, stream>>>(attn_bf, (long)S * S, valueT, (long)D * S,
                                        out, (long)S * D);
}

// Round 15
// 426.241 us; speedup vs baseline: 1.1334x; 1.0180x over previous
//
#include <hip/hip_runtime.h>

// ---------------------------------------------------------------------------
// RVMixtureSynthesizers: q = query@Wq^T + bq ; k = key@Wk^T + bk
//   energy = q@k^T + attn_bias ; attention = softmax(energy) ; out = attention@value
// Outputs: out [16,1024,1024] fp32, attention [16,1024,1024] fp32 (concat in d_out)
//
// R14 = R13 + dispatch consolidation:
//  - gemm32_proj2: both projections in ONE grid-512 dispatch (op bit from the
//    swizzled block id; K-loop/ledger/epilogue byte-identical to R13 EPI=0).
//  - fused_converts: all 4 split-conversions in ONE grid-5120 dispatch.
// Split-bf16 (hh+hl+lh) for proj and QK^T; PV plain bf16 on 32x32 MFMA.
// ---------------------------------------------------------------------------

#define AS1 __attribute__((address_space(1)))
#define AS3 __attribute__((address_space(3)))
#define VMCNT(n) asm volatile("s_waitcnt vmcnt(" #n ")" ::: "memory")
#define LGKM(n)  asm volatile("s_waitcnt lgkmcnt(" #n ")" ::: "memory")
#define SBARRIER asm volatile("s_barrier" ::: "memory")
#define SB0 __builtin_amdgcn_sched_barrier(0)

typedef __bf16 bf16;
typedef __bf16 bf16x4 __attribute__((ext_vector_type(4)));
typedef __bf16 bf16x8 __attribute__((ext_vector_type(8)));
typedef float  f32x4  __attribute__((ext_vector_type(4)));
typedef float  f32x16 __attribute__((ext_vector_type(16)));

constexpr int BATCH = 16;
constexpr int S = 1024;
constexpr int D = 1024;
constexpr long NBSD = (long)BATCH * S * D;   // 16777216

constexpr int GBM = 256, GBN = 256, GBK = 32;
constexpr int NTK = 1024 / GBK;              // 32 K-tiles
constexpr int ARR = GBM * GBK;               // 8192 elems = 16 KB per array

__device__ __forceinline__ void stage16(const bf16* src, const bf16* dst) {
  __builtin_amdgcn_global_load_lds((const AS1 void*)src, (AS3 void*)dst, 16, 0, 0);
}

// ---------------------------------------------------------------------------
// fp32 -> (hi,lo) bf16 split, shared body (grid-stride within a block range)
__device__ __forceinline__ void conv_body(
    const float* __restrict__ in, bf16* __restrict__ hi, bf16* __restrict__ lo,
    int n4, int bid, int nb) {
  int i = bid * 256 + threadIdx.x;
  const int stride = nb * 256;
  for (; i < n4; i += stride) {
    f32x4 x = ((const f32x4*)in)[i];
    bf16x4 h, l;
#pragma unroll
    for (int j = 0; j < 4; ++j) {
      float v = x[j];
      bf16 hh = (bf16)v;
      h[j] = hh;
      l[j] = (bf16)(v - (float)hh);
    }
    ((bf16x4*)hi)[i] = h;
    ((bf16x4*)lo)[i] = l;
  }
}

// All 4 independent split-conversions in one dispatch (block-range dispatch).
__global__ __launch_bounds__(256) void fused_converts(
    const float* __restrict__ query, const float* __restrict__ key,
    const float* __restrict__ Wq, const float* __restrict__ Wk,
    bf16* __restrict__ q_hi, bf16* __restrict__ q_lo,
    bf16* __restrict__ k_hi, bf16* __restrict__ k_lo,
    bf16* __restrict__ Wq_hi, bf16* __restrict__ Wq_lo,
    bf16* __restrict__ Wk_hi, bf16* __restrict__ Wk_lo) {
  const int b = blockIdx.x;
  if (b < 2048)       conv_body(query, q_hi, q_lo, (int)(NBSD / 4), b, 2048);
  else if (b < 4096)  conv_body(key,  k_hi, k_lo, (int)(NBSD / 4), b - 2048, 2048);
  else if (b < 4608)  conv_body(Wq, Wq_hi, Wq_lo, D * D / 4, b - 4096, 512);
  else                conv_body(Wk, Wk_hi, Wk_lo, D * D / 4, b - 4608, 512);
}

// ---------------------------------------------------------------------------
__global__ __launch_bounds__(256) void transpose_convert(
    const float* __restrict__ v, bf16* __restrict__ vT) {
  __shared__ float tile[32][33];
  const int b = blockIdx.z;
  const int t0 = blockIdx.y * 32, d0 = blockIdx.x * 32;
  const int tx = threadIdx.x & 31, ty = threadIdx.x >> 5;
  const float* src = v + (long)b * S * D;
#pragma unroll
  for (int i = 0; i < 4; ++i)
    tile[ty + i * 8][tx] = src[(long)(t0 + ty + i * 8) * D + d0 + tx];
  __syncthreads();
  bf16* dst = vT + (long)b * D * S;
#pragma unroll
  for (int i = 0; i < 4; ++i)
    dst[(long)(d0 + ty + i * 8) * S + t0 + tx] = (bf16)tile[tx][ty + i * 8];
}

// ---------------------------------------------------------------------------
// Shared machinery macros for the 32x32 split GEMM (R5/R13-verified).
#define STGM(slot, arr, base, koff, rr) \
  stage16((base) + (koff) + (long)(rr) * 131072, \
          lds + ((slot) * 4 + (arr)) * ARR + (rr) * 4096 + dstoff)

#define CLUSTERM(AF, BF) \
  __builtin_amdgcn_s_setprio(1); \
  _Pragma("unroll") \
  for (int s = 0; s < 2; ++s) \
    _Pragma("unroll") \
    for (int i = 0; i < 4; ++i) \
      _Pragma("unroll") \
      for (int j = 0; j < 2; ++j) \
        acc[i][j] = __builtin_amdgcn_mfma_f32_32x32x16_bf16(AF[i][s], BF[j][s], acc[i][j], 0, 0, 0); \
  __builtin_amdgcn_s_setprio(0)

// K-loop body shared textually between the two split kernels (verbatim R13).
#define SPLIT_KLOOP \
  STGM(0, 0, A_h + asrc, 0, 0); STGM(0, 0, A_h + asrc, 0, 1); \
  STGM(0, 2, B_h + bsrc, 0, 0); STGM(0, 2, B_h + bsrc, 0, 1); \
  STGM(0, 3, B_l + bsrc, 0, 0); STGM(0, 3, B_l + bsrc, 0, 1); \
  STGM(0, 1, A_l + asrc, 0, 0); STGM(0, 1, A_l + asrc, 0, 1); \
  VMCNT(4); \
  SBARRIER; \
  for (int t = 0; t < NTK; ++t) { \
    const int cur = t & 1, nxt = cur ^ 1; \
    const long kn = (long)(t + 1) * GBK; \
    const bool pf = (t + 1 < NTK); \
    const bf16* lA_h = lds + (cur * 4 + 0) * ARR; \
    const bf16* lA_l = lds + (cur * 4 + 1) * ARR; \
    const bf16* lB_h = lds + (cur * 4 + 2) * ARR; \
    const bf16* lB_l = lds + (cur * 4 + 3) * ARR; \
    _Pragma("unroll") \
    for (int i = 0; i < 4; ++i) \
      _Pragma("unroll") \
      for (int s = 0; s < 2; ++s) ah[i][s] = *(const bf16x8*)&lA_h[aoff[i][s]]; \
    _Pragma("unroll") \
    for (int j = 0; j < 2; ++j) \
      _Pragma("unroll") \
      for (int s = 0; s < 2; ++s) bh[j][s] = *(const bf16x8*)&lB_h[boff[j][s]]; \
    if (pf) { \
      STGM(nxt, 0, A_h + asrc, kn, 0); STGM(nxt, 0, A_h + asrc, kn, 1); \
      STGM(nxt, 2, B_h + bsrc, kn, 0); STGM(nxt, 2, B_h + bsrc, kn, 1); \
      VMCNT(6); \
    } else { VMCNT(2); } \
    SBARRIER; LGKM(0); SB0; \
    CLUSTERM(ah, bh); \
    SBARRIER; \
    _Pragma("unroll") \
    for (int j = 0; j < 2; ++j) \
      _Pragma("unroll") \
      for (int s = 0; s < 2; ++s) bl[j][s] = *(const bf16x8*)&lB_l[boff[j][s]]; \
    if (pf) { \
      STGM(nxt, 3, B_l + bsrc, kn, 0); STGM(nxt, 3, B_l + bsrc, kn, 1); \
      VMCNT(6); \
    } else { VMCNT(0); } \
    SBARRIER; LGKM(0); SB0; \
    CLUSTERM(ah, bl); \
    SBARRIER; \
    _Pragma("unroll") \
    for (int i = 0; i < 4; ++i) \
      _Pragma("unroll") \
      for (int s = 0; s < 2; ++s) al[i][s] = *(const bf16x8*)&lA_l[aoff[i][s]]; \
    if (pf) { \
      STGM(nxt, 1, A_l + asrc, kn, 0); STGM(nxt, 1, A_l + asrc, kn, 1); \
      VMCNT(4); \
    } \
    SBARRIER; LGKM(0); SB0; \
    CLUSTERM(al, bh); \
    SBARRIER; \
  }

#define SPLIT_PREAMBLE \
  const int tid = threadIdx.x; \
  const int lane = tid & 63, wid = tid >> 6; \
  const int wr = wid >> 2, wc = wid & 3; \
  const int lr = lane & 31; \
  const int lk = lane >> 5; \
  const int srow = tid >> 2; \
  const int csw = ((tid & 3) ^ ((srow >> 1) & 3)) * 8; \
  const int dstoff = wid * 512; \
  int aoff[4][2], boff[2][2]; \
  _Pragma("unroll") \
  for (int i = 0; i < 4; ++i) { \
    const int r = wr * 128 + i * 32 + lr; \
    _Pragma("unroll") \
    for (int s = 0; s < 2; ++s) \
      aoff[i][s] = r * 32 + (((2 * s + lk) ^ ((r >> 1) & 3)) * 8); \
  } \
  _Pragma("unroll") \
  for (int j = 0; j < 2; ++j) { \
    const int r = wc * 64 + j * 32 + lr; \
    _Pragma("unroll") \
    for (int s = 0; s < 2; ++s) \
      boff[j][s] = r * 32 + (((2 * s + lk) ^ ((r >> 1) & 3)) * 8); \
  } \
  f32x16 acc[4][2] = {}; \
  bf16x8 ah[4][2], al[4][2], bh[2][2], bl[2][2];

// ---------------------------------------------------------------------------
// BOTH projections in one grid-512 dispatch. op = swizzled-id >> 8 selects
// {query,Wq,bq,q-out} vs {key,Wk,bk,k-out}. Everything else = R13 EPI=0.
__global__ __launch_bounds__(512, 2) void gemm32_proj2(
    const bf16* __restrict__ qh, const bf16* __restrict__ ql,
    const bf16* __restrict__ kh, const bf16* __restrict__ kl,
    const bf16* __restrict__ Wqh, const bf16* __restrict__ Wql,
    const bf16* __restrict__ Wkh, const bf16* __restrict__ Wkl,
    const float* __restrict__ bq, const float* __restrict__ bk,
    bf16* __restrict__ qoh, bf16* __restrict__ qol,
    bf16* __restrict__ koh, bf16* __restrict__ kol) {
  __shared__ bf16 lds[2 * 4 * ARR];   // 128 KB

  SPLIT_PREAMBLE

  // bijective swizzle over 512 blocks (512 % 8 == 0)
  const int w = blockIdx.x;
  const int swz = (w & 7) * 64 + (w >> 3);
  const int op = swz >> 8;            // 0 = q-proj, 1 = k-proj
  const int rem = swz & 255;
  const int by = rem >> 2, bx = rem & 3;
  const long brow = (long)by * GBM, bcol = (long)bx * GBN;

  const bf16* A_h = op ? kh : qh;
  const bf16* A_l = op ? kl : ql;
  const bf16* B_h = op ? Wkh : Wqh;
  const bf16* B_l = op ? Wkl : Wql;
  const float* bias = op ? bk : bq;
  bf16* Ch = op ? koh : qoh;
  bf16* Cl = op ? kol : qol;

  const long asrc = (brow + srow) * 1024 + csw;
  const long bsrc = (bcol + srow) * 1024 + csw;

  SPLIT_KLOOP

  // Epilogue (EPI=0 path): split-bf16 out + col bias.
#pragma unroll
  for (int j = 0; j < 2; ++j) {
    const long col = bcol + wc * 64 + j * 32 + lr;
    const float bv = bias[col];
#pragma unroll
    for (int i = 0; i < 4; ++i) {
      const long row0 = brow + wr * 128 + i * 32 + 4 * lk;
#pragma unroll
      for (int r = 0; r < 16; ++r) {
        const long row = row0 + (r & 3) + 8 * (r >> 2);
        const float c = acc[i][j][r] + bv;
        const bf16 h = (bf16)c;
        const bf16 l = (bf16)(c - (float)h);
        const long idx = row * 1024 + col;
        Ch[idx] = h;
        Cl[idx] = l;
      }
    }
  }
}

// ---------------------------------------------------------------------------
// Energy split GEMM (R13 EPI=1, unchanged): fp32 out + attn_bias, batched z.
__global__ __launch_bounds__(512, 2) void gemm32_energy(
    const bf16* __restrict__ Ah_g, const bf16* __restrict__ Al_g, long a_bs,
    const bf16* __restrict__ Bh_g, const bf16* __restrict__ Bl_g, long b_bs,
    const float* __restrict__ bias,
    float* __restrict__ Cf, long c_bs) {
  __shared__ bf16 lds[2 * 4 * ARR];   // 128 KB

  SPLIT_PREAMBLE

  const int w = blockIdx.x;
  const int swz = (w & 7) * 32 + (w >> 3);
  const int z = swz >> 4, by = (swz >> 2) & 3, bx = swz & 3;
  const long brow = (long)by * GBM, bcol = (long)bx * GBN;

  const bf16* A_h = Ah_g + (long)z * a_bs;
  const bf16* A_l = Al_g + (long)z * a_bs;
  const bf16* B_h = Bh_g + (long)z * b_bs;
  const bf16* B_l = Bl_g + (long)z * b_bs;

  const long asrc = (brow + srow) * 1024 + csw;
  const long bsrc = (bcol + srow) * 1024 + csw;

  SPLIT_KLOOP

  float* Cz = Cf + (long)z * c_bs;
#pragma unroll
  for (int j = 0; j < 2; ++j) {
    const long col = bcol + wc * 64 + j * 32 + lr;
#pragma unroll
    for (int i = 0; i < 4; ++i) {
      const long row0 = brow + wr * 128 + i * 32 + 4 * lk;
#pragma unroll
      for (int r = 0; r < 16; ++r) {
        const long row = row0 + (r & 3) + 8 * (r >> 2);
        Cz[row * 1024 + col] = acc[i][j][r] + bias[row * 1024 + col];
      }
    }
  }
}

// ---------------------------------------------------------------------------
// Plain bf16 GEMM (PV) on 32x32 MFMA (verbatim R13). 1 phase/K-tile,
// counted vmcnt(4); LDS 2 bufs x {A,B} = 64 KB.
__global__ __launch_bounds__(512, 2) void gemm32_plain(
    const bf16* __restrict__ A_g, long a_bs,
    const bf16* __restrict__ B_g, long b_bs,
    float* __restrict__ C, long c_bs) {
  __shared__ bf16 lds[2 * 2 * ARR];   // 64 KB

  const int tid = threadIdx.x;
  const int lane = tid & 63, wid = tid >> 6;
  const int wr = wid >> 2, wc = wid & 3;
  const int lr = lane & 31;
  const int lk = lane >> 5;

  const int w = blockIdx.x;
  const int swz = (w & 7) * 32 + (w >> 3);
  const int z = swz >> 4, by = (swz >> 2) & 3, bx = swz & 3;
  const long brow = (long)by * GBM, bcol = (long)bx * GBN;

  const bf16* A = A_g + (long)z * a_bs;
  const bf16* B = B_g + (long)z * b_bs;

  const int srow = tid >> 2;
  const int csw = ((tid & 3) ^ ((srow >> 1) & 3)) * 8;
  const long asrc = (brow + srow) * 1024 + csw;
  const long bsrc = (bcol + srow) * 1024 + csw;
  const int dstoff = wid * 512;

  int aoff[4][2], boff[2][2];
#pragma unroll
  for (int i = 0; i < 4; ++i) {
    const int r = wr * 128 + i * 32 + lr;
#pragma unroll
    for (int s = 0; s < 2; ++s)
      aoff[i][s] = r * 32 + (((2 * s + lk) ^ ((r >> 1) & 3)) * 8);
  }
#pragma unroll
  for (int j = 0; j < 2; ++j) {
    const int r = wc * 64 + j * 32 + lr;
#pragma unroll
    for (int s = 0; s < 2; ++s)
      boff[j][s] = r * 32 + (((2 * s + lk) ^ ((r >> 1) & 3)) * 8);
  }

  f32x16 acc[4][2] = {};
  bf16x8 af[4][2], bf_[2][2];

#define STG2(slot, arr, base, koff, rr) \
  stage16((base) + (koff) + (long)(rr) * 131072, \
          lds + ((slot) * 2 + (arr)) * ARR + (rr) * 4096 + dstoff)

  STG2(0, 0, A + asrc, 0, 0); STG2(0, 0, A + asrc, 0, 1);
  STG2(0, 1, B + bsrc, 0, 0); STG2(0, 1, B + bsrc, 0, 1);

  for (int t = 0; t < NTK; ++t) {
    const int cur = t & 1, nxt = cur ^ 1;
    const bf16* lA = lds + (cur * 2 + 0) * ARR;
    const bf16* lB = lds + (cur * 2 + 1) * ARR;

    if (t + 1 < NTK) {
      const long kn = (long)(t + 1) * GBK;
      STG2(nxt, 0, A + asrc, kn, 0); STG2(nxt, 0, A + asrc, kn, 1);
      STG2(nxt, 1, B + bsrc, kn, 0); STG2(nxt, 1, B + bsrc, kn, 1);
      VMCNT(4);
    } else {
      VMCNT(0);
    }
    SB0;
    SBARRIER;

#pragma unroll
    for (int i = 0; i < 4; ++i)
#pragma unroll
      for (int s = 0; s < 2; ++s) af[i][s] = *(const bf16x8*)&lA[aoff[i][s]];
#pragma unroll
    for (int j = 0; j < 2; ++j)
#pragma unroll
      for (int s = 0; s < 2; ++s) bf_[j][s] = *(const bf16x8*)&lB[boff[j][s]];
    LGKM(0); SB0;
    __builtin_amdgcn_s_setprio(1);
#pragma unroll
    for (int s = 0; s < 2; ++s)
#pragma unroll
      for (int i = 0; i < 4; ++i)
#pragma unroll
        for (int j = 0; j < 2; ++j)
          acc[i][j] = __builtin_amdgcn_mfma_f32_32x32x16_bf16(af[i][s], bf_[j][s], acc[i][j], 0, 0, 0);
    __builtin_amdgcn_s_setprio(0);

    SBARRIER;
  }
#undef STG2

  float* Cz = C + (long)z * c_bs;
#pragma unroll
  for (int j = 0; j < 2; ++j) {
    const long col = bcol + wc * 64 + j * 32 + lr;
#pragma unroll
    for (int i = 0; i < 4; ++i) {
      const long row0 = brow + wr * 128 + i * 32 + 4 * lk;
#pragma unroll
      for (int r = 0; r < 16; ++r) {
        const long row = row0 + (r & 3) + 8 * (r >> 2);
        Cz[row * 1024 + col] = acc[i][j][r];
      }
    }
  }
}

// ---------------------------------------------------------------------------
__global__ __launch_bounds__(256) void softmax_rows(
    float* __restrict__ attn, bf16* __restrict__ attn_bf) {
  const long row = blockIdx.x;
  float* p = attn + row * 1024;
  const int tid = threadIdx.x, lane = tid & 63, wid = tid >> 6;

  f32x4 x = ((const f32x4*)p)[tid];
  float m = fmaxf(fmaxf(x[0], x[1]), fmaxf(x[2], x[3]));
#pragma unroll
  for (int off = 32; off; off >>= 1) m = fmaxf(m, __shfl_xor(m, off));
  __shared__ float redm[4];
  if (lane == 0) redm[wid] = m;
  __syncthreads();
  m = fmaxf(fmaxf(redm[0], redm[1]), fmaxf(redm[2], redm[3]));

  f32x4 e;
#pragma unroll
  for (int j = 0; j < 4; ++j) e[j] = __expf(x[j] - m);
  float s = e[0] + e[1] + e[2] + e[3];
#pragma unroll
  for (int off = 32; off; off >>= 1) s += __shfl_xor(s, off);
  __shared__ float reds[4];
  if (lane == 0) reds[wid] = s;
  __syncthreads();
  s = reds[0] + reds[1] + reds[2] + reds[3];

  const float inv = 1.0f / s;
  f32x4 r;
  bf16x4 rb;
#pragma unroll
  for (int j = 0; j < 4; ++j) {
    r[j] = e[j] * inv;
    rb[j] = (bf16)r[j];
  }
  ((f32x4*)p)[tid] = r;
  ((bf16x4*)(attn_bf + row * 1024))[tid] = rb;
}

// ---------------------------------------------------------------------------
extern "C" void kernel_launch(void* const* d_in, const int* in_sizes, int n_in,
                              void* d_out, int out_size, void* d_ws, size_t ws_size,
                              hipStream_t stream) {
  const float* query     = (const float*)d_in[0];
  const float* key       = (const float*)d_in[1];
  const float* value     = (const float*)d_in[2];
  const float* attn_bias = (const float*)d_in[3];
  const float* Wq        = (const float*)d_in[4];
  const float* bq        = (const float*)d_in[5];
  const float* Wk        = (const float*)d_in[6];
  const float* bk        = (const float*)d_in[7];

  float* out  = (float*)d_out;          // [16,1024,1024]
  float* attn = out + NBSD;             // [16,1024,1024]

  // ws carve (bf16 elements). Total = 6*NBSD + 4*D*D = 200 MiB.
  bf16* ws    = (bf16*)d_ws;
  bf16* q_hi  = ws;
  bf16* q_lo  = ws + NBSD;
  bf16* k_hi  = ws + 2 * NBSD;
  bf16* k_lo  = ws + 3 * NBSD;
  bf16* Wq_hi = ws + 4 * NBSD;
  bf16* Wq_lo = Wq_hi + (long)D * D;
  bf16* Wk_hi = Wq_lo + (long)D * D;
  bf16* Wk_lo = Wk_hi + (long)D * D;
  bf16* scr   = Wk_lo + (long)D * D;    // 2*NBSD scratch
  bf16* key_hi = scr;
  bf16* key_lo = scr + NBSD;
  bf16* valueT  = scr;                  // reused after key splits die
  bf16* attn_bf = scr + NBSD;
  bf16* query_hi = (bf16*)d_out;        // lives in `out` region until PV
  bf16* query_lo = query_hi + NBSD;

  // 1) all split conversions in ONE dispatch
  fused_converts<<<5120, 256, 0, stream>>>(query, key, Wq, Wk,
                                           query_hi, query_lo, key_hi, key_lo,
                                           Wq_hi, Wq_lo, Wk_hi, Wk_lo);

  // 2) BOTH projections in ONE grid-512 dispatch
  gemm32_proj2<<<512, 512, 0, stream>>>(query_hi, query_lo, key_hi, key_lo,
                                        Wq_hi, Wq_lo, Wk_hi, Wk_lo,
                                        bq, bk,
                                        q_hi, q_lo, k_hi, k_lo);

  // 3) value transpose (key splits now dead)
  transpose_convert<<<dim3(32, 32, 16), 256, 0, stream>>>(value, valueT);

  // 4) energy = q k^T + bias (grid 16 z x 4x4 = 256 blocks)
  gemm32_energy<<<256, 512, 0, stream>>>(q_hi, q_lo, (long)S * D, k_hi, k_lo, (long)S * D,
                                         attn_bias, attn, (long)S * S);

  // 5) softmax in place + bf16 copy
  softmax_rows<<<BATCH * S, 256, 0, stream>>>(attn, attn_bf);

  // 6) out = attention @ value (32x32 MFMA)
  gemm32_plain<<<256, 512, 0, stream>>>(attn_bf, (long)S * S, valueT, (long)D * S,
                                        out, (long)S * D);
}

// Round 16
// 422.305 us; speedup vs baseline: 1.1440x; 1.0093x over previous
//
#include <hip/hip_runtime.h>

// ---------------------------------------------------------------------------
// RVMixtureSynthesizers: q = query@Wq^T + bq ; k = key@Wk^T + bk
//   energy = q@k^T + attn_bias ; attention = softmax(energy) ; out = attention@value
// Outputs: out [16,1024,1024] fp32, attention [16,1024,1024] fp32 (concat in d_out)
//
// R15 = R14 verbatim (terminal configuration, 426.2 us measured):
//  - fused_converts: all 4 split-conversions in ONE dispatch (HBM-roof).
//  - gemm32_proj2: both projections in ONE grid-512 dispatch (MfmaUtil 47).
//  - gemm32_energy / gemm32_plain: R5-verified 32x32 split/plain GEMMs.
//  - softmax_rows / transpose_convert: HBM-roof memory kernels.
// Split-bf16 (hh+hl+lh) for proj and QK^T; PV plain bf16 on 32x32 MFMA.
// ---------------------------------------------------------------------------

#define AS1 __attribute__((address_space(1)))
#define AS3 __attribute__((address_space(3)))
#define VMCNT(n) asm volatile("s_waitcnt vmcnt(" #n ")" ::: "memory")
#define LGKM(n)  asm volatile("s_waitcnt lgkmcnt(" #n ")" ::: "memory")
#define SBARRIER asm volatile("s_barrier" ::: "memory")
#define SB0 __builtin_amdgcn_sched_barrier(0)

typedef __bf16 bf16;
typedef __bf16 bf16x4 __attribute__((ext_vector_type(4)));
typedef __bf16 bf16x8 __attribute__((ext_vector_type(8)));
typedef float  f32x4  __attribute__((ext_vector_type(4)));
typedef float  f32x16 __attribute__((ext_vector_type(16)));

constexpr int BATCH = 16;
constexpr int S = 1024;
constexpr int D = 1024;
constexpr long NBSD = (long)BATCH * S * D;   // 16777216

constexpr int GBM = 256, GBN = 256, GBK = 32;
constexpr int NTK = 1024 / GBK;              // 32 K-tiles
constexpr int ARR = GBM * GBK;               // 8192 elems = 16 KB per array

__device__ __forceinline__ void stage16(const bf16* src, const bf16* dst) {
  __builtin_amdgcn_global_load_lds((const AS1 void*)src, (AS3 void*)dst, 16, 0, 0);
}

// ---------------------------------------------------------------------------
// fp32 -> (hi,lo) bf16 split, shared body (grid-stride within a block range)
__device__ __forceinline__ void conv_body(
    const float* __restrict__ in, bf16* __restrict__ hi, bf16* __restrict__ lo,
    int n4, int bid, int nb) {
  int i = bid * 256 + threadIdx.x;
  const int stride = nb * 256;
  for (; i < n4; i += stride) {
    f32x4 x = ((const f32x4*)in)[i];
    bf16x4 h, l;
#pragma unroll
    for (int j = 0; j < 4; ++j) {
      float v = x[j];
      bf16 hh = (bf16)v;
      h[j] = hh;
      l[j] = (bf16)(v - (float)hh);
    }
    ((bf16x4*)hi)[i] = h;
    ((bf16x4*)lo)[i] = l;
  }
}

// All 4 independent split-conversions in one dispatch (block-range dispatch).
__global__ __launch_bounds__(256) void fused_converts(
    const float* __restrict__ query, const float* __restrict__ key,
    const float* __restrict__ Wq, const float* __restrict__ Wk,
    bf16* __restrict__ q_hi, bf16* __restrict__ q_lo,
    bf16* __restrict__ k_hi, bf16* __restrict__ k_lo,
    bf16* __restrict__ Wq_hi, bf16* __restrict__ Wq_lo,
    bf16* __restrict__ Wk_hi, bf16* __restrict__ Wk_lo) {
  const int b = blockIdx.x;
  if (b < 2048)       conv_body(query, q_hi, q_lo, (int)(NBSD / 4), b, 2048);
  else if (b < 4096)  conv_body(key,  k_hi, k_lo, (int)(NBSD / 4), b - 2048, 2048);
  else if (b < 4608)  conv_body(Wq, Wq_hi, Wq_lo, D * D / 4, b - 4096, 512);
  else                conv_body(Wk, Wk_hi, Wk_lo, D * D / 4, b - 4608, 512);
}

// ---------------------------------------------------------------------------
__global__ __launch_bounds__(256) void transpose_convert(
    const float* __restrict__ v, bf16* __restrict__ vT) {
  __shared__ float tile[32][33];
  const int b = blockIdx.z;
  const int t0 = blockIdx.y * 32, d0 = blockIdx.x * 32;
  const int tx = threadIdx.x & 31, ty = threadIdx.x >> 5;
  const float* src = v + (long)b * S * D;
#pragma unroll
  for (int i = 0; i < 4; ++i)
    tile[ty + i * 8][tx] = src[(long)(t0 + ty + i * 8) * D + d0 + tx];
  __syncthreads();
  bf16* dst = vT + (long)b * D * S;
#pragma unroll
  for (int i = 0; i < 4; ++i)
    dst[(long)(d0 + ty + i * 8) * S + t0 + tx] = (bf16)tile[tx][ty + i * 8];
}

// ---------------------------------------------------------------------------
// Shared machinery macros for the 32x32 split GEMM (R5/R13-verified).
#define STGM(slot, arr, base, koff, rr) \
  stage16((base) + (koff) + (long)(rr) * 131072, \
          lds + ((slot) * 4 + (arr)) * ARR + (rr) * 4096 + dstoff)

#define CLUSTERM(AF, BF) \
  __builtin_amdgcn_s_setprio(1); \
  _Pragma("unroll") \
  for (int s = 0; s < 2; ++s) \
    _Pragma("unroll") \
    for (int i = 0; i < 4; ++i) \
      _Pragma("unroll") \
      for (int j = 0; j < 2; ++j) \
        acc[i][j] = __builtin_amdgcn_mfma_f32_32x32x16_bf16(AF[i][s], BF[j][s], acc[i][j], 0, 0, 0); \
  __builtin_amdgcn_s_setprio(0)

// K-loop body shared textually between the two split kernels (verbatim R13).
#define SPLIT_KLOOP \
  STGM(0, 0, A_h + asrc, 0, 0); STGM(0, 0, A_h + asrc, 0, 1); \
  STGM(0, 2, B_h + bsrc, 0, 0); STGM(0, 2, B_h + bsrc, 0, 1); \
  STGM(0, 3, B_l + bsrc, 0, 0); STGM(0, 3, B_l + bsrc, 0, 1); \
  STGM(0, 1, A_l + asrc, 0, 0); STGM(0, 1, A_l + asrc, 0, 1); \
  VMCNT(4); \
  SBARRIER; \
  for (int t = 0; t < NTK; ++t) { \
    const int cur = t & 1, nxt = cur ^ 1; \
    const long kn = (long)(t + 1) * GBK; \
    const bool pf = (t + 1 < NTK); \
    const bf16* lA_h = lds + (cur * 4 + 0) * ARR; \
    const bf16* lA_l = lds + (cur * 4 + 1) * ARR; \
    const bf16* lB_h = lds + (cur * 4 + 2) * ARR; \
    const bf16* lB_l = lds + (cur * 4 + 3) * ARR; \
    _Pragma("unroll") \
    for (int i = 0; i < 4; ++i) \
      _Pragma("unroll") \
      for (int s = 0; s < 2; ++s) ah[i][s] = *(const bf16x8*)&lA_h[aoff[i][s]]; \
    _Pragma("unroll") \
    for (int j = 0; j < 2; ++j) \
      _Pragma("unroll") \
      for (int s = 0; s < 2; ++s) bh[j][s] = *(const bf16x8*)&lB_h[boff[j][s]]; \
    if (pf) { \
      STGM(nxt, 0, A_h + asrc, kn, 0); STGM(nxt, 0, A_h + asrc, kn, 1); \
      STGM(nxt, 2, B_h + bsrc, kn, 0); STGM(nxt, 2, B_h + bsrc, kn, 1); \
      VMCNT(6); \
    } else { VMCNT(2); } \
    SBARRIER; LGKM(0); SB0; \
    CLUSTERM(ah, bh); \
    SBARRIER; \
    _Pragma("unroll") \
    for (int j = 0; j < 2; ++j) \
      _Pragma("unroll") \
      for (int s = 0; s < 2; ++s) bl[j][s] = *(const bf16x8*)&lB_l[boff[j][s]]; \
    if (pf) { \
      STGM(nxt, 3, B_l + bsrc, kn, 0); STGM(nxt, 3, B_l + bsrc, kn, 1); \
      VMCNT(6); \
    } else { VMCNT(0); } \
    SBARRIER; LGKM(0); SB0; \
    CLUSTERM(ah, bl); \
    SBARRIER; \
    _Pragma("unroll") \
    for (int i = 0; i < 4; ++i) \
      _Pragma("unroll") \
      for (int s = 0; s < 2; ++s) al[i][s] = *(const bf16x8*)&lA_l[aoff[i][s]]; \
    if (pf) { \
      STGM(nxt, 1, A_l + asrc, kn, 0); STGM(nxt, 1, A_l + asrc, kn, 1); \
      VMCNT(4); \
    } \
    SBARRIER; LGKM(0); SB0; \
    CLUSTERM(al, bh); \
    SBARRIER; \
  }

#define SPLIT_PREAMBLE \
  const int tid = threadIdx.x; \
  const int lane = tid & 63, wid = tid >> 6; \
  const int wr = wid >> 2, wc = wid & 3; \
  const int lr = lane & 31; \
  const int lk = lane >> 5; \
  const int srow = tid >> 2; \
  const int csw = ((tid & 3) ^ ((srow >> 1) & 3)) * 8; \
  const int dstoff = wid * 512; \
  int aoff[4][2], boff[2][2]; \
  _Pragma("unroll") \
  for (int i = 0; i < 4; ++i) { \
    const int r = wr * 128 + i * 32 + lr; \
    _Pragma("unroll") \
    for (int s = 0; s < 2; ++s) \
      aoff[i][s] = r * 32 + (((2 * s + lk) ^ ((r >> 1) & 3)) * 8); \
  } \
  _Pragma("unroll") \
  for (int j = 0; j < 2; ++j) { \
    const int r = wc * 64 + j * 32 + lr; \
    _Pragma("unroll") \
    for (int s = 0; s < 2; ++s) \
      boff[j][s] = r * 32 + (((2 * s + lk) ^ ((r >> 1) & 3)) * 8); \
  } \
  f32x16 acc[4][2] = {}; \
  bf16x8 ah[4][2], al[4][2], bh[2][2], bl[2][2];

// ---------------------------------------------------------------------------
// BOTH projections in one grid-512 dispatch. op = swizzled-id >> 8 selects
// {query,Wq,bq,q-out} vs {key,Wk,bk,k-out}. Everything else = R13 EPI=0.
__global__ __launch_bounds__(512, 2) void gemm32_proj2(
    const bf16* __restrict__ qh, const bf16* __restrict__ ql,
    const bf16* __restrict__ kh, const bf16* __restrict__ kl,
    const bf16* __restrict__ Wqh, const bf16* __restrict__ Wql,
    const bf16* __restrict__ Wkh, const bf16* __restrict__ Wkl,
    const float* __restrict__ bq, const float* __restrict__ bk,
    bf16* __restrict__ qoh, bf16* __restrict__ qol,
    bf16* __restrict__ koh, bf16* __restrict__ kol) {
  __shared__ bf16 lds[2 * 4 * ARR];   // 128 KB

  SPLIT_PREAMBLE

  // bijective swizzle over 512 blocks (512 % 8 == 0)
  const int w = blockIdx.x;
  const int swz = (w & 7) * 64 + (w >> 3);
  const int op = swz >> 8;            // 0 = q-proj, 1 = k-proj
  const int rem = swz & 255;
  const int by = rem >> 2, bx = rem & 3;
  const long brow = (long)by * GBM, bcol = (long)bx * GBN;

  const bf16* A_h = op ? kh : qh;
  const bf16* A_l = op ? kl : ql;
  const bf16* B_h = op ? Wkh : Wqh;
  const bf16* B_l = op ? Wkl : Wql;
  const float* bias = op ? bk : bq;
  bf16* Ch = op ? koh : qoh;
  bf16* Cl = op ? kol : qol;

  const long asrc = (brow + srow) * 1024 + csw;
  const long bsrc = (bcol + srow) * 1024 + csw;

  SPLIT_KLOOP

  // Epilogue (EPI=0 path): split-bf16 out + col bias.
#pragma unroll
  for (int j = 0; j < 2; ++j) {
    const long col = bcol + wc * 64 + j * 32 + lr;
    const float bv = bias[col];
#pragma unroll
    for (int i = 0; i < 4; ++i) {
      const long row0 = brow + wr * 128 + i * 32 + 4 * lk;
#pragma unroll
      for (int r = 0; r < 16; ++r) {
        const long row = row0 + (r & 3) + 8 * (r >> 2);
        const float c = acc[i][j][r] + bv;
        const bf16 h = (bf16)c;
        const bf16 l = (bf16)(c - (float)h);
        const long idx = row * 1024 + col;
        Ch[idx] = h;
        Cl[idx] = l;
      }
    }
  }
}

// ---------------------------------------------------------------------------
// Energy split GEMM (R13 EPI=1, unchanged): fp32 out + attn_bias, batched z.
__global__ __launch_bounds__(512, 2) void gemm32_energy(
    const bf16* __restrict__ Ah_g, const bf16* __restrict__ Al_g, long a_bs,
    const bf16* __restrict__ Bh_g, const bf16* __restrict__ Bl_g, long b_bs,
    const float* __restrict__ bias,
    float* __restrict__ Cf, long c_bs) {
  __shared__ bf16 lds[2 * 4 * ARR];   // 128 KB

  SPLIT_PREAMBLE

  const int w = blockIdx.x;
  const int swz = (w & 7) * 32 + (w >> 3);
  const int z = swz >> 4, by = (swz >> 2) & 3, bx = swz & 3;
  const long brow = (long)by * GBM, bcol = (long)bx * GBN;

  const bf16* A_h = Ah_g + (long)z * a_bs;
  const bf16* A_l = Al_g + (long)z * a_bs;
  const bf16* B_h = Bh_g + (long)z * b_bs;
  const bf16* B_l = Bl_g + (long)z * b_bs;

  const long asrc = (brow + srow) * 1024 + csw;
  const long bsrc = (bcol + srow) * 1024 + csw;

  SPLIT_KLOOP

  float* Cz = Cf + (long)z * c_bs;
#pragma unroll
  for (int j = 0; j < 2; ++j) {
    const long col = bcol + wc * 64 + j * 32 + lr;
#pragma unroll
    for (int i = 0; i < 4; ++i) {
      const long row0 = brow + wr * 128 + i * 32 + 4 * lk;
#pragma unroll
      for (int r = 0; r < 16; ++r) {
        const long row = row0 + (r & 3) + 8 * (r >> 2);
        Cz[row * 1024 + col] = acc[i][j][r] + bias[row * 1024 + col];
      }
    }
  }
}

// ---------------------------------------------------------------------------
// Plain bf16 GEMM (PV) on 32x32 MFMA (verbatim R13). 1 phase/K-tile,
// counted vmcnt(4); LDS 2 bufs x {A,B} = 64 KB.
__global__ __launch_bounds__(512, 2) void gemm32_plain(
    const bf16* __restrict__ A_g, long a_bs,
    const bf16* __restrict__ B_g, long b_bs,
    float* __restrict__ C, long c_bs) {
  __shared__ bf16 lds[2 * 2 * ARR];   // 64 KB

  const int tid = threadIdx.x;
  const int lane = tid & 63, wid = tid >> 6;
  const int wr = wid >> 2, wc = wid & 3;
  const int lr = lane & 31;
  const int lk = lane >> 5;

  const int w = blockIdx.x;
  const int swz = (w & 7) * 32 + (w >> 3);
  const int z = swz >> 4, by = (swz >> 2) & 3, bx = swz & 3;
  const long brow = (long)by * GBM, bcol = (long)bx * GBN;

  const bf16* A = A_g + (long)z * a_bs;
  const bf16* B = B_g + (long)z * b_bs;

  const int srow = tid >> 2;
  const int csw = ((tid & 3) ^ ((srow >> 1) & 3)) * 8;
  const long asrc = (brow + srow) * 1024 + csw;
  const long bsrc = (bcol + srow) * 1024 + csw;
  const int dstoff = wid * 512;

  int aoff[4][2], boff[2][2];
#pragma unroll
  for (int i = 0; i < 4; ++i) {
    const int r = wr * 128 + i * 32 + lr;
#pragma unroll
    for (int s = 0; s < 2; ++s)
      aoff[i][s] = r * 32 + (((2 * s + lk) ^ ((r >> 1) & 3)) * 8);
  }
#pragma unroll
  for (int j = 0; j < 2; ++j) {
    const int r = wc * 64 + j * 32 + lr;
#pragma unroll
    for (int s = 0; s < 2; ++s)
      boff[j][s] = r * 32 + (((2 * s + lk) ^ ((r >> 1) & 3)) * 8);
  }

  f32x16 acc[4][2] = {};
  bf16x8 af[4][2], bf_[2][2];

#define STG2(slot, arr, base, koff, rr) \
  stage16((base) + (koff) + (long)(rr) * 131072, \
          lds + ((slot) * 2 + (arr)) * ARR + (rr) * 4096 + dstoff)

  STG2(0, 0, A + asrc, 0, 0); STG2(0, 0, A + asrc, 0, 1);
  STG2(0, 1, B + bsrc, 0, 0); STG2(0, 1, B + bsrc, 0, 1);

  for (int t = 0; t < NTK; ++t) {
    const int cur = t & 1, nxt = cur ^ 1;
    const bf16* lA = lds + (cur * 2 + 0) * ARR;
    const bf16* lB = lds + (cur * 2 + 1) * ARR;

    if (t + 1 < NTK) {
      const long kn = (long)(t + 1) * GBK;
      STG2(nxt, 0, A + asrc, kn, 0); STG2(nxt, 0, A + asrc, kn, 1);
      STG2(nxt, 1, B + bsrc, kn, 0); STG2(nxt, 1, B + bsrc, kn, 1);
      VMCNT(4);
    } else {
      VMCNT(0);
    }
    SB0;
    SBARRIER;

#pragma unroll
    for (int i = 0; i < 4; ++i)
#pragma unroll
      for (int s = 0; s < 2; ++s) af[i][s] = *(const bf16x8*)&lA[aoff[i][s]];
#pragma unroll
    for (int j = 0; j < 2; ++j)
#pragma unroll
      for (int s = 0; s < 2; ++s) bf_[j][s] = *(const bf16x8*)&lB[boff[j][s]];
    LGKM(0); SB0;
    __builtin_amdgcn_s_setprio(1);
#pragma unroll
    for (int s = 0; s < 2; ++s)
#pragma unroll
      for (int i = 0; i < 4; ++i)
#pragma unroll
        for (int j = 0; j < 2; ++j)
          acc[i][j] = __builtin_amdgcn_mfma_f32_32x32x16_bf16(af[i][s], bf_[j][s], acc[i][j], 0, 0, 0);
    __builtin_amdgcn_s_setprio(0);

    SBARRIER;
  }
#undef STG2

  float* Cz = C + (long)z * c_bs;
#pragma unroll
  for (int j = 0; j < 2; ++j) {
    const long col = bcol + wc * 64 + j * 32 + lr;
#pragma unroll
    for (int i = 0; i < 4; ++i) {
      const long row0 = brow + wr * 128 + i * 32 + 4 * lk;
#pragma unroll
      for (int r = 0; r < 16; ++r) {
        const long row = row0 + (r & 3) + 8 * (r >> 2);
        Cz[row * 1024 + col] = acc[i][j][r];
      }
    }
  }
}

// ---------------------------------------------------------------------------
__global__ __launch_bounds__(256) void softmax_rows(
    float* __restrict__ attn, bf16* __restrict__ attn_bf) {
  const long row = blockIdx.x;
  float* p = attn + row * 1024;
  const int tid = threadIdx.x, lane = tid & 63, wid = tid >> 6;

  f32x4 x = ((const f32x4*)p)[tid];
  float m = fmaxf(fmaxf(x[0], x[1]), fmaxf(x[2], x[3]));
#pragma unroll
  for (int off = 32; off; off >>= 1) m = fmaxf(m, __shfl_xor(m, off));
  __shared__ float redm[4];
  if (lane == 0) redm[wid] = m;
  __syncthreads();
  m = fmaxf(fmaxf(redm[0], redm[1]), fmaxf(redm[2], redm[3]));

  f32x4 e;
#pragma unroll
  for (int j = 0; j < 4; ++j) e[j] = __expf(x[j] - m);
  float s = e[0] + e[1] + e[2] + e[3];
#pragma unroll
  for (int off = 32; off; off >>= 1) s += __shfl_xor(s, off);
  __shared__ float reds[4];
  if (lane == 0) reds[wid] = s;
  __syncthreads();
  s = reds[0] + reds[1] + reds[2] + reds[3];

  const float inv = 1.0f / s;
  f32x4 r;
  bf16x4 rb;
#pragma unroll
  for (int j = 0; j < 4; ++j) {
    r[j] = e[j] * inv;
    rb[j] = (bf16)r[j];
  }
  ((f32x4*)p)[tid] = r;
  ((bf16x4*)(attn_bf + row * 1024))[tid] = rb;
}

// ---------------------------------------------------------------------------
extern "C" void kernel_launch(void* const* d_in, const int* in_sizes, int n_in,
                              void* d_out, int out_size, void* d_ws, size_t ws_size,
                              hipStream_t stream) {
  const float* query     = (const float*)d_in[0];
  const float* key       = (const float*)d_in[1];
  const float* value     = (const float*)d_in[2];
  const float* attn_bias = (const float*)d_in[3];
  const float* Wq        = (const float*)d_in[4];
  const float* bq        = (const float*)d_in[5];
  const float* Wk        = (const float*)d_in[6];
  const float* bk        = (const float*)d_in[7];

  float* out  = (float*)d_out;          // [16,1024,1024]
  float* attn = out + NBSD;             // [16,1024,1024]

  // ws carve (bf16 elements). Total = 6*NBSD + 4*D*D = 200 MiB.
  bf16* ws    = (bf16*)d_ws;
  bf16* q_hi  = ws;
  bf16* q_lo  = ws + NBSD;
  bf16* k_hi  = ws + 2 * NBSD;
  bf16* k_lo  = ws + 3 * NBSD;
  bf16* Wq_hi = ws + 4 * NBSD;
  bf16* Wq_lo = Wq_hi + (long)D * D;
  bf16* Wk_hi = Wq_lo + (long)D * D;
  bf16* Wk_lo = Wk_hi + (long)D * D;
  bf16* scr   = Wk_lo + (long)D * D;    // 2*NBSD scratch
  bf16* key_hi = scr;
  bf16* key_lo = scr + NBSD;
  bf16* valueT  = scr;                  // reused after key splits die
  bf16* attn_bf = scr + NBSD;
  bf16* query_hi = (bf16*)d_out;        // lives in `out` region until PV
  bf16* query_lo = query_hi + NBSD;

  // 1) all split conversions in ONE dispatch
  fused_converts<<<5120, 256, 0, stream>>>(query, key, Wq, Wk,
                                           query_hi, query_lo, key_hi, key_lo,
                                           Wq_hi, Wq_lo, Wk_hi, Wk_lo);

  // 2) BOTH projections in ONE grid-512 dispatch
  gemm32_proj2<<<512, 512, 0, stream>>>(query_hi, query_lo, key_hi, key_lo,
                                        Wq_hi, Wq_lo, Wk_hi, Wk_lo,
                                        bq, bk,
                                        q_hi, q_lo, k_hi, k_lo);

  // 3) value transpose (key splits now dead)
  transpose_convert<<<dim3(32, 32, 16), 256, 0, stream>>>(value, valueT);

  // 4) energy = q k^T + bias (grid 16 z x 4x4 = 256 blocks)
  gemm32_energy<<<256, 512, 0, stream>>>(q_hi, q_lo, (long)S * D, k_hi, k_lo, (long)S * D,
                                         attn_bias, attn, (long)S * S);

  // 5) softmax in place + bf16 copy
  softmax_rows<<<BATCH * S, 256, 0, stream>>>(attn, attn_bf);

  // 6) out = attention @ value (32x32 MFMA)
  gemm32_plain<<<256, 512, 0, stream>>>(attn_bf, (long)S * S, valueT, (long)D * S,
                                        out, (long)S * D);
}

// Round 17
// 418.856 us; speedup vs baseline: 1.1534x; 1.0082x over previous
//
#include <hip/hip_runtime.h>

// ---------------------------------------------------------------------------
// RVMixtureSynthesizers: q = query@Wq^T + bq ; k = key@Wk^T + bk
//   energy = q@k^T + attn_bias ; attention = softmax(energy) ; out = attention@value
// Outputs: out [16,1024,1024] fp32, attention [16,1024,1024] fp32 (concat in d_out)
//
// R16 = R15 with the value-transpose freed from its false (aliasing-only)
// dependency and merged into the fused conversion dispatch:
//  - key INPUT splits now live in d_out.attn (dead before energy writes it),
//    valueT/attn_bf get dedicated ws space -> no aliasing anywhere.
//  - fused_converts_t: 4 split-conversions + value transpose in ONE dispatch.
// GEMM/softmax kernels byte-identical to R15 (verified best).
// ---------------------------------------------------------------------------

#define AS1 __attribute__((address_space(1)))
#define AS3 __attribute__((address_space(3)))
#define VMCNT(n) asm volatile("s_waitcnt vmcnt(" #n ")" ::: "memory")
#define LGKM(n)  asm volatile("s_waitcnt lgkmcnt(" #n ")" ::: "memory")
#define SBARRIER asm volatile("s_barrier" ::: "memory")
#define SB0 __builtin_amdgcn_sched_barrier(0)

typedef __bf16 bf16;
typedef __bf16 bf16x4 __attribute__((ext_vector_type(4)));
typedef __bf16 bf16x8 __attribute__((ext_vector_type(8)));
typedef float  f32x4  __attribute__((ext_vector_type(4)));
typedef float  f32x16 __attribute__((ext_vector_type(16)));

constexpr int BATCH = 16;
constexpr int S = 1024;
constexpr int D = 1024;
constexpr long NBSD = (long)BATCH * S * D;   // 16777216

constexpr int GBM = 256, GBN = 256, GBK = 32;
constexpr int NTK = 1024 / GBK;              // 32 K-tiles
constexpr int ARR = GBM * GBK;               // 8192 elems = 16 KB per array

__device__ __forceinline__ void stage16(const bf16* src, const bf16* dst) {
  __builtin_amdgcn_global_load_lds((const AS1 void*)src, (AS3 void*)dst, 16, 0, 0);
}

// ---------------------------------------------------------------------------
// fp32 -> (hi,lo) bf16 split, shared body (grid-stride within a block range)
__device__ __forceinline__ void conv_body(
    const float* __restrict__ in, bf16* __restrict__ hi, bf16* __restrict__ lo,
    int n4, int bid, int nb) {
  int i = bid * 256 + threadIdx.x;
  const int stride = nb * 256;
  for (; i < n4; i += stride) {
    f32x4 x = ((const f32x4*)in)[i];
    bf16x4 h, l;
#pragma unroll
    for (int j = 0; j < 4; ++j) {
      float v = x[j];
      bf16 hh = (bf16)v;
      h[j] = hh;
      l[j] = (bf16)(v - (float)hh);
    }
    ((bf16x4*)hi)[i] = h;
    ((bf16x4*)lo)[i] = l;
  }
}

// 4 split-conversions + value transpose in ONE dispatch (block-range dispatch).
// Blocks [0,2048): query conv; [2048,4096): key conv; [4096,4608): Wq;
// [4608,5120): Wk; [5120,21504): value transpose (flattened 32x32x16 tiles).
__global__ __launch_bounds__(256) void fused_converts_t(
    const float* __restrict__ query, const float* __restrict__ key,
    const float* __restrict__ Wq, const float* __restrict__ Wk,
    const float* __restrict__ value,
    bf16* __restrict__ q_hi, bf16* __restrict__ q_lo,
    bf16* __restrict__ k_hi, bf16* __restrict__ k_lo,
    bf16* __restrict__ Wq_hi, bf16* __restrict__ Wq_lo,
    bf16* __restrict__ Wk_hi, bf16* __restrict__ Wk_lo,
    bf16* __restrict__ vT) {
  const int b = blockIdx.x;
  if (b < 2048) {
    conv_body(query, q_hi, q_lo, (int)(NBSD / 4), b, 2048);
  } else if (b < 4096) {
    conv_body(key, k_hi, k_lo, (int)(NBSD / 4), b - 2048, 2048);
  } else if (b < 4608) {
    conv_body(Wq, Wq_hi, Wq_lo, D * D / 4, b - 4096, 512);
  } else if (b < 5120) {
    conv_body(Wk, Wk_hi, Wk_lo, D * D / 4, b - 4608, 512);
  } else {
    // value [bz][t][d] fp32 -> vT [bz][d][t] bf16, 32x32 tile per block
    __shared__ float tile[32][33];
    const int tb = b - 5120;              // 0..16383
    const int bz = tb >> 10;              // 1024 tiles per batch
    const int rem = tb & 1023;
    const int t0 = (rem >> 5) * 32, d0 = (rem & 31) * 32;
    const int tx = threadIdx.x & 31, ty = threadIdx.x >> 5;  // 32 x 8
    const float* src = value + (long)bz * S * D;
#pragma unroll
    for (int i = 0; i < 4; ++i)
      tile[ty + i * 8][tx] = src[(long)(t0 + ty + i * 8) * D + d0 + tx];
    __syncthreads();
    bf16* dst = vT + (long)bz * D * S;
#pragma unroll
    for (int i = 0; i < 4; ++i)
      dst[(long)(d0 + ty + i * 8) * S + t0 + tx] = (bf16)tile[tx][ty + i * 8];
  }
}

// ---------------------------------------------------------------------------
// Shared machinery macros for the 32x32 split GEMM (R5/R13-verified).
#define STGM(slot, arr, base, koff, rr) \
  stage16((base) + (koff) + (long)(rr) * 131072, \
          lds + ((slot) * 4 + (arr)) * ARR + (rr) * 4096 + dstoff)

#define CLUSTERM(AF, BF) \
  __builtin_amdgcn_s_setprio(1); \
  _Pragma("unroll") \
  for (int s = 0; s < 2; ++s) \
    _Pragma("unroll") \
    for (int i = 0; i < 4; ++i) \
      _Pragma("unroll") \
      for (int j = 0; j < 2; ++j) \
        acc[i][j] = __builtin_amdgcn_mfma_f32_32x32x16_bf16(AF[i][s], BF[j][s], acc[i][j], 0, 0, 0); \
  __builtin_amdgcn_s_setprio(0)

// K-loop body shared textually between the two split kernels (verbatim R13).
#define SPLIT_KLOOP \
  STGM(0, 0, A_h + asrc, 0, 0); STGM(0, 0, A_h + asrc, 0, 1); \
  STGM(0, 2, B_h + bsrc, 0, 0); STGM(0, 2, B_h + bsrc, 0, 1); \
  STGM(0, 3, B_l + bsrc, 0, 0); STGM(0, 3, B_l + bsrc, 0, 1); \
  STGM(0, 1, A_l + asrc, 0, 0); STGM(0, 1, A_l + asrc, 0, 1); \
  VMCNT(4); \
  SBARRIER; \
  for (int t = 0; t < NTK; ++t) { \
    const int cur = t & 1, nxt = cur ^ 1; \
    const long kn = (long)(t + 1) * GBK; \
    const bool pf = (t + 1 < NTK); \
    const bf16* lA_h = lds + (cur * 4 + 0) * ARR; \
    const bf16* lA_l = lds + (cur * 4 + 1) * ARR; \
    const bf16* lB_h = lds + (cur * 4 + 2) * ARR; \
    const bf16* lB_l = lds + (cur * 4 + 3) * ARR; \
    _Pragma("unroll") \
    for (int i = 0; i < 4; ++i) \
      _Pragma("unroll") \
      for (int s = 0; s < 2; ++s) ah[i][s] = *(const bf16x8*)&lA_h[aoff[i][s]]; \
    _Pragma("unroll") \
    for (int j = 0; j < 2; ++j) \
      _Pragma("unroll") \
      for (int s = 0; s < 2; ++s) bh[j][s] = *(const bf16x8*)&lB_h[boff[j][s]]; \
    if (pf) { \
      STGM(nxt, 0, A_h + asrc, kn, 0); STGM(nxt, 0, A_h + asrc, kn, 1); \
      STGM(nxt, 2, B_h + bsrc, kn, 0); STGM(nxt, 2, B_h + bsrc, kn, 1); \
      VMCNT(6); \
    } else { VMCNT(2); } \
    SBARRIER; LGKM(0); SB0; \
    CLUSTERM(ah, bh); \
    SBARRIER; \
    _Pragma("unroll") \
    for (int j = 0; j < 2; ++j) \
      _Pragma("unroll") \
      for (int s = 0; s < 2; ++s) bl[j][s] = *(const bf16x8*)&lB_l[boff[j][s]]; \
    if (pf) { \
      STGM(nxt, 3, B_l + bsrc, kn, 0); STGM(nxt, 3, B_l + bsrc, kn, 1); \
      VMCNT(6); \
    } else { VMCNT(0); } \
    SBARRIER; LGKM(0); SB0; \
    CLUSTERM(ah, bl); \
    SBARRIER; \
    _Pragma("unroll") \
    for (int i = 0; i < 4; ++i) \
      _Pragma("unroll") \
      for (int s = 0; s < 2; ++s) al[i][s] = *(const bf16x8*)&lA_l[aoff[i][s]]; \
    if (pf) { \
      STGM(nxt, 1, A_l + asrc, kn, 0); STGM(nxt, 1, A_l + asrc, kn, 1); \
      VMCNT(4); \
    } \
    SBARRIER; LGKM(0); SB0; \
    CLUSTERM(al, bh); \
    SBARRIER; \
  }

#define SPLIT_PREAMBLE \
  const int tid = threadIdx.x; \
  const int lane = tid & 63, wid = tid >> 6; \
  const int wr = wid >> 2, wc = wid & 3; \
  const int lr = lane & 31; \
  const int lk = lane >> 5; \
  const int srow = tid >> 2; \
  const int csw = ((tid & 3) ^ ((srow >> 1) & 3)) * 8; \
  const int dstoff = wid * 512; \
  int aoff[4][2], boff[2][2]; \
  _Pragma("unroll") \
  for (int i = 0; i < 4; ++i) { \
    const int r = wr * 128 + i * 32 + lr; \
    _Pragma("unroll") \
    for (int s = 0; s < 2; ++s) \
      aoff[i][s] = r * 32 + (((2 * s + lk) ^ ((r >> 1) & 3)) * 8); \
  } \
  _Pragma("unroll") \
  for (int j = 0; j < 2; ++j) { \
    const int r = wc * 64 + j * 32 + lr; \
    _Pragma("unroll") \
    for (int s = 0; s < 2; ++s) \
      boff[j][s] = r * 32 + (((2 * s + lk) ^ ((r >> 1) & 3)) * 8); \
  } \
  f32x16 acc[4][2] = {}; \
  bf16x8 ah[4][2], al[4][2], bh[2][2], bl[2][2];

// ---------------------------------------------------------------------------
// BOTH projections in one grid-512 dispatch (verbatim R15).
__global__ __launch_bounds__(512, 2) void gemm32_proj2(
    const bf16* __restrict__ qh, const bf16* __restrict__ ql,
    const bf16* __restrict__ kh, const bf16* __restrict__ kl,
    const bf16* __restrict__ Wqh, const bf16* __restrict__ Wql,
    const bf16* __restrict__ Wkh, const bf16* __restrict__ Wkl,
    const float* __restrict__ bq, const float* __restrict__ bk,
    bf16* __restrict__ qoh, bf16* __restrict__ qol,
    bf16* __restrict__ koh, bf16* __restrict__ kol) {
  __shared__ bf16 lds[2 * 4 * ARR];   // 128 KB

  SPLIT_PREAMBLE

  // bijective swizzle over 512 blocks (512 % 8 == 0)
  const int w = blockIdx.x;
  const int swz = (w & 7) * 64 + (w >> 3);
  const int op = swz >> 8;            // 0 = q-proj, 1 = k-proj
  const int rem = swz & 255;
  const int by = rem >> 2, bx = rem & 3;
  const long brow = (long)by * GBM, bcol = (long)bx * GBN;

  const bf16* A_h = op ? kh : qh;
  const bf16* A_l = op ? kl : ql;
  const bf16* B_h = op ? Wkh : Wqh;
  const bf16* B_l = op ? Wkl : Wql;
  const float* bias = op ? bk : bq;
  bf16* Ch = op ? koh : qoh;
  bf16* Cl = op ? kol : qol;

  const long asrc = (brow + srow) * 1024 + csw;
  const long bsrc = (bcol + srow) * 1024 + csw;

  SPLIT_KLOOP

  // Epilogue (EPI=0 path): split-bf16 out + col bias.
#pragma unroll
  for (int j = 0; j < 2; ++j) {
    const long col = bcol + wc * 64 + j * 32 + lr;
    const float bv = bias[col];
#pragma unroll
    for (int i = 0; i < 4; ++i) {
      const long row0 = brow + wr * 128 + i * 32 + 4 * lk;
#pragma unroll
      for (int r = 0; r < 16; ++r) {
        const long row = row0 + (r & 3) + 8 * (r >> 2);
        const float c = acc[i][j][r] + bv;
        const bf16 h = (bf16)c;
        const bf16 l = (bf16)(c - (float)h);
        const long idx = row * 1024 + col;
        Ch[idx] = h;
        Cl[idx] = l;
      }
    }
  }
}

// ---------------------------------------------------------------------------
// Energy split GEMM (verbatim R15): fp32 out + attn_bias, batched z.
__global__ __launch_bounds__(512, 2) void gemm32_energy(
    const bf16* __restrict__ Ah_g, const bf16* __restrict__ Al_g, long a_bs,
    const bf16* __restrict__ Bh_g, const bf16* __restrict__ Bl_g, long b_bs,
    const float* __restrict__ bias,
    float* __restrict__ Cf, long c_bs) {
  __shared__ bf16 lds[2 * 4 * ARR];   // 128 KB

  SPLIT_PREAMBLE

  const int w = blockIdx.x;
  const int swz = (w & 7) * 32 + (w >> 3);
  const int z = swz >> 4, by = (swz >> 2) & 3, bx = swz & 3;
  const long brow = (long)by * GBM, bcol = (long)bx * GBN;

  const bf16* A_h = Ah_g + (long)z * a_bs;
  const bf16* A_l = Al_g + (long)z * a_bs;
  const bf16* B_h = Bh_g + (long)z * b_bs;
  const bf16* B_l = Bl_g + (long)z * b_bs;

  const long asrc = (brow + srow) * 1024 + csw;
  const long bsrc = (bcol + srow) * 1024 + csw;

  SPLIT_KLOOP

  float* Cz = Cf + (long)z * c_bs;
#pragma unroll
  for (int j = 0; j < 2; ++j) {
    const long col = bcol + wc * 64 + j * 32 + lr;
#pragma unroll
    for (int i = 0; i < 4; ++i) {
      const long row0 = brow + wr * 128 + i * 32 + 4 * lk;
#pragma unroll
      for (int r = 0; r < 16; ++r) {
        const long row = row0 + (r & 3) + 8 * (r >> 2);
        Cz[row * 1024 + col] = acc[i][j][r] + bias[row * 1024 + col];
      }
    }
  }
}

// ---------------------------------------------------------------------------
// Plain bf16 GEMM (PV) on 32x32 MFMA (verbatim R15).
__global__ __launch_bounds__(512, 2) void gemm32_plain(
    const bf16* __restrict__ A_g, long a_bs,
    const bf16* __restrict__ B_g, long b_bs,
    float* __restrict__ C, long c_bs) {
  __shared__ bf16 lds[2 * 2 * ARR];   // 64 KB

  const int tid = threadIdx.x;
  const int lane = tid & 63, wid = tid >> 6;
  const int wr = wid >> 2, wc = wid & 3;
  const int lr = lane & 31;
  const int lk = lane >> 5;

  const int w = blockIdx.x;
  const int swz = (w & 7) * 32 + (w >> 3);
  const int z = swz >> 4, by = (swz >> 2) & 3, bx = swz & 3;
  const long brow = (long)by * GBM, bcol = (long)bx * GBN;

  const bf16* A = A_g + (long)z * a_bs;
  const bf16* B = B_g + (long)z * b_bs;

  const int srow = tid >> 2;
  const int csw = ((tid & 3) ^ ((srow >> 1) & 3)) * 8;
  const long asrc = (brow + srow) * 1024 + csw;
  const long bsrc = (bcol + srow) * 1024 + csw;
  const int dstoff = wid * 512;

  int aoff[4][2], boff[2][2];
#pragma unroll
  for (int i = 0; i < 4; ++i) {
    const int r = wr * 128 + i * 32 + lr;
#pragma unroll
    for (int s = 0; s < 2; ++s)
      aoff[i][s] = r * 32 + (((2 * s + lk) ^ ((r >> 1) & 3)) * 8);
  }
#pragma unroll
  for (int j = 0; j < 2; ++j) {
    const int r = wc * 64 + j * 32 + lr;
#pragma unroll
    for (int s = 0; s < 2; ++s)
      boff[j][s] = r * 32 + (((2 * s + lk) ^ ((r >> 1) & 3)) * 8);
  }

  f32x16 acc[4][2] = {};
  bf16x8 af[4][2], bf_[2][2];

#define STG2(slot, arr, base, koff, rr) \
  stage16((base) + (koff) + (long)(rr) * 131072, \
          lds + ((slot) * 2 + (arr)) * ARR + (rr) * 4096 + dstoff)

  STG2(0, 0, A + asrc, 0, 0); STG2(0, 0, A + asrc, 0, 1);
  STG2(0, 1, B + bsrc, 0, 0); STG2(0, 1, B + bsrc, 0, 1);

  for (int t = 0; t < NTK; ++t) {
    const int cur = t & 1, nxt = cur ^ 1;
    const bf16* lA = lds + (cur * 2 + 0) * ARR;
    const bf16* lB = lds + (cur * 2 + 1) * ARR;

    if (t + 1 < NTK) {
      const long kn = (long)(t + 1) * GBK;
      STG2(nxt, 0, A + asrc, kn, 0); STG2(nxt, 0, A + asrc, kn, 1);
      STG2(nxt, 1, B + bsrc, kn, 0); STG2(nxt, 1, B + bsrc, kn, 1);
      VMCNT(4);
    } else {
      VMCNT(0);
    }
    SB0;
    SBARRIER;

#pragma unroll
    for (int i = 0; i < 4; ++i)
#pragma unroll
      for (int s = 0; s < 2; ++s) af[i][s] = *(const bf16x8*)&lA[aoff[i][s]];
#pragma unroll
    for (int j = 0; j < 2; ++j)
#pragma unroll
      for (int s = 0; s < 2; ++s) bf_[j][s] = *(const bf16x8*)&lB[boff[j][s]];
    LGKM(0); SB0;
    __builtin_amdgcn_s_setprio(1);
#pragma unroll
    for (int s = 0; s < 2; ++s)
#pragma unroll
      for (int i = 0; i < 4; ++i)
#pragma unroll
        for (int j = 0; j < 2; ++j)
          acc[i][j] = __builtin_amdgcn_mfma_f32_32x32x16_bf16(af[i][s], bf_[j][s], acc[i][j], 0, 0, 0);
    __builtin_amdgcn_s_setprio(0);

    SBARRIER;
  }
#undef STG2

  float* Cz = C + (long)z * c_bs;
#pragma unroll
  for (int j = 0; j < 2; ++j) {
    const long col = bcol + wc * 64 + j * 32 + lr;
#pragma unroll
    for (int i = 0; i < 4; ++i) {
      const long row0 = brow + wr * 128 + i * 32 + 4 * lk;
#pragma unroll
      for (int r = 0; r < 16; ++r) {
        const long row = row0 + (r & 3) + 8 * (r >> 2);
        Cz[row * 1024 + col] = acc[i][j][r];
      }
    }
  }
}

// ---------------------------------------------------------------------------
__global__ __launch_bounds__(256) void softmax_rows(
    float* __restrict__ attn, bf16* __restrict__ attn_bf) {
  const long row = blockIdx.x;
  float* p = attn + row * 1024;
  const int tid = threadIdx.x, lane = tid & 63, wid = tid >> 6;

  f32x4 x = ((const f32x4*)p)[tid];
  float m = fmaxf(fmaxf(x[0], x[1]), fmaxf(x[2], x[3]));
#pragma unroll
  for (int off = 32; off; off >>= 1) m = fmaxf(m, __shfl_xor(m, off));
  __shared__ float redm[4];
  if (lane == 0) redm[wid] = m;
  __syncthreads();
  m = fmaxf(fmaxf(redm[0], redm[1]), fmaxf(redm[2], redm[3]));

  f32x4 e;
#pragma unroll
  for (int j = 0; j < 4; ++j) e[j] = __expf(x[j] - m);
  float s = e[0] + e[1] + e[2] + e[3];
#pragma unroll
  for (int off = 32; off; off >>= 1) s += __shfl_xor(s, off);
  __shared__ float reds[4];
  if (lane == 0) reds[wid] = s;
  __syncthreads();
  s = reds[0] + reds[1] + reds[2] + reds[3];

  const float inv = 1.0f / s;
  f32x4 r;
  bf16x4 rb;
#pragma unroll
  for (int j = 0; j < 4; ++j) {
    r[j] = e[j] * inv;
    rb[j] = (bf16)r[j];
  }
  ((f32x4*)p)[tid] = r;
  ((bf16x4*)(attn_bf + row * 1024))[tid] = rb;
}

// ---------------------------------------------------------------------------
extern "C" void kernel_launch(void* const* d_in, const int* in_sizes, int n_in,
                              void* d_out, int out_size, void* d_ws, size_t ws_size,
                              hipStream_t stream) {
  const float* query     = (const float*)d_in[0];
  const float* key       = (const float*)d_in[1];
  const float* value     = (const float*)d_in[2];
  const float* attn_bias = (const float*)d_in[3];
  const float* Wq        = (const float*)d_in[4];
  const float* bq        = (const float*)d_in[5];
  const float* Wk        = (const float*)d_in[6];
  const float* bk        = (const float*)d_in[7];

  float* out  = (float*)d_out;          // [16,1024,1024]
  float* attn = out + NBSD;             // [16,1024,1024]

  // ws carve (bf16 elements): projected splits + W splits + valueT + attn_bf
  // = 6*NBSD + 4*D*D = 200 MiB (no aliasing).
  bf16* ws    = (bf16*)d_ws;
  bf16* q_hi  = ws;                     // projected q splits
  bf16* q_lo  = ws + NBSD;
  bf16* k_hi  = ws + 2 * NBSD;          // projected k splits
  bf16* k_lo  = ws + 3 * NBSD;
  bf16* Wq_hi = ws + 4 * NBSD;
  bf16* Wq_lo = Wq_hi + (long)D * D;
  bf16* Wk_hi = Wq_lo + (long)D * D;
  bf16* Wk_lo = Wk_hi + (long)D * D;
  bf16* valueT  = Wk_lo + (long)D * D;  // dedicated (no aliasing)
  bf16* attn_bf = valueT + NBSD;
  // INPUT splits live in d_out (dead before their regions are written):
  //   query splits in `out` (PV writes out last);
  //   key splits in `attn` (energy writes attn after proj2 consumed them).
  bf16* query_hi = (bf16*)out;
  bf16* query_lo = query_hi + NBSD;
  bf16* key_hi   = (bf16*)attn;
  bf16* key_lo   = key_hi + NBSD;

  // 1) all split conversions + value transpose in ONE dispatch
  fused_converts_t<<<21504, 256, 0, stream>>>(query, key, Wq, Wk, value,
                                              query_hi, query_lo, key_hi, key_lo,
                                              Wq_hi, Wq_lo, Wk_hi, Wk_lo,
                                              valueT);

  // 2) BOTH projections in ONE grid-512 dispatch
  gemm32_proj2<<<512, 512, 0, stream>>>(query_hi, query_lo, key_hi, key_lo,
                                        Wq_hi, Wq_lo, Wk_hi, Wk_lo,
                                        bq, bk,
                                        q_hi, q_lo, k_hi, k_lo);

  // 3) energy = q k^T + bias (key input splits in attn now dead)
  gemm32_energy<<<256, 512, 0, stream>>>(q_hi, q_lo, (long)S * D, k_hi, k_lo, (long)S * D,
                                         attn_bias, attn, (long)S * S);

  // 4) softmax in place + bf16 copy
  softmax_rows<<<BATCH * S, 256, 0, stream>>>(attn, attn_bf);

  // 5) out = attention @ value (query input splits in out now dead)
  gemm32_plain<<<256, 512, 0, stream>>>(attn_bf, (long)S * S, valueT, (long)D * S,
                                        out, (long)S * D);
}

// Round 18
// 418.146 us; speedup vs baseline: 1.1554x; 1.0017x over previous
//
#include <hip/hip_runtime.h>

// ---------------------------------------------------------------------------
// RVMixtureSynthesizers: q = query@Wq^T + bq ; k = key@Wk^T + bk
//   energy = q@k^T + attn_bias ; attention = softmax(energy) ; out = attention@value
// Outputs: out [16,1024,1024] fp32, attention [16,1024,1024] fp32 (concat in d_out)
//
// FINAL (R16, 418.9 us measured; session 550 -> 419):
//  - fused_converts_t: 4 split-conversions + value transpose in ONE dispatch
//    (HBM-roof; key input splits live in d_out.attn, query's in d_out.out).
//  - gemm32_proj2: both projections in ONE grid-512 dispatch (MfmaUtil 47).
//  - gemm32_energy / gemm32_plain: R5-verified 32x32 split/plain GEMMs
//    (3-phase hh/hl/lh, counted vmcnt 6/6/4, chunk-XOR LDS swizzle).
//  - softmax_rows: HBM-roof row softmax + bf16 copy for PV.
// Split-bf16 (hh+hl+lh) for proj and QK^T keeps energy error ~1e-3;
// PV plain bf16. absmax 0.03125 vs threshold 0.108.
// ---------------------------------------------------------------------------

#define AS1 __attribute__((address_space(1)))
#define AS3 __attribute__((address_space(3)))
#define VMCNT(n) asm volatile("s_waitcnt vmcnt(" #n ")" ::: "memory")
#define LGKM(n)  asm volatile("s_waitcnt lgkmcnt(" #n ")" ::: "memory")
#define SBARRIER asm volatile("s_barrier" ::: "memory")
#define SB0 __builtin_amdgcn_sched_barrier(0)

typedef __bf16 bf16;
typedef __bf16 bf16x4 __attribute__((ext_vector_type(4)));
typedef __bf16 bf16x8 __attribute__((ext_vector_type(8)));
typedef float  f32x4  __attribute__((ext_vector_type(4)));
typedef float  f32x16 __attribute__((ext_vector_type(16)));

constexpr int BATCH = 16;
constexpr int S = 1024;
constexpr int D = 1024;
constexpr long NBSD = (long)BATCH * S * D;   // 16777216

constexpr int GBM = 256, GBN = 256, GBK = 32;
constexpr int NTK = 1024 / GBK;              // 32 K-tiles
constexpr int ARR = GBM * GBK;               // 8192 elems = 16 KB per array

__device__ __forceinline__ void stage16(const bf16* src, const bf16* dst) {
  __builtin_amdgcn_global_load_lds((const AS1 void*)src, (AS3 void*)dst, 16, 0, 0);
}

// ---------------------------------------------------------------------------
// fp32 -> (hi,lo) bf16 split, shared body (grid-stride within a block range)
__device__ __forceinline__ void conv_body(
    const float* __restrict__ in, bf16* __restrict__ hi, bf16* __restrict__ lo,
    int n4, int bid, int nb) {
  int i = bid * 256 + threadIdx.x;
  const int stride = nb * 256;
  for (; i < n4; i += stride) {
    f32x4 x = ((const f32x4*)in)[i];
    bf16x4 h, l;
#pragma unroll
    for (int j = 0; j < 4; ++j) {
      float v = x[j];
      bf16 hh = (bf16)v;
      h[j] = hh;
      l[j] = (bf16)(v - (float)hh);
    }
    ((bf16x4*)hi)[i] = h;
    ((bf16x4*)lo)[i] = l;
  }
}

// 4 split-conversions + value transpose in ONE dispatch (block-range dispatch).
// Blocks [0,2048): query conv; [2048,4096): key conv; [4096,4608): Wq;
// [4608,5120): Wk; [5120,21504): value transpose (flattened 32x32x16 tiles).
__global__ __launch_bounds__(256) void fused_converts_t(
    const float* __restrict__ query, const float* __restrict__ key,
    const float* __restrict__ Wq, const float* __restrict__ Wk,
    const float* __restrict__ value,
    bf16* __restrict__ q_hi, bf16* __restrict__ q_lo,
    bf16* __restrict__ k_hi, bf16* __restrict__ k_lo,
    bf16* __restrict__ Wq_hi, bf16* __restrict__ Wq_lo,
    bf16* __restrict__ Wk_hi, bf16* __restrict__ Wk_lo,
    bf16* __restrict__ vT) {
  const int b = blockIdx.x;
  if (b < 2048) {
    conv_body(query, q_hi, q_lo, (int)(NBSD / 4), b, 2048);
  } else if (b < 4096) {
    conv_body(key, k_hi, k_lo, (int)(NBSD / 4), b - 2048, 2048);
  } else if (b < 4608) {
    conv_body(Wq, Wq_hi, Wq_lo, D * D / 4, b - 4096, 512);
  } else if (b < 5120) {
    conv_body(Wk, Wk_hi, Wk_lo, D * D / 4, b - 4608, 512);
  } else {
    // value [bz][t][d] fp32 -> vT [bz][d][t] bf16, 32x32 tile per block
    __shared__ float tile[32][33];
    const int tb = b - 5120;              // 0..16383
    const int bz = tb >> 10;              // 1024 tiles per batch
    const int rem = tb & 1023;
    const int t0 = (rem >> 5) * 32, d0 = (rem & 31) * 32;
    const int tx = threadIdx.x & 31, ty = threadIdx.x >> 5;  // 32 x 8
    const float* src = value + (long)bz * S * D;
#pragma unroll
    for (int i = 0; i < 4; ++i)
      tile[ty + i * 8][tx] = src[(long)(t0 + ty + i * 8) * D + d0 + tx];
    __syncthreads();
    bf16* dst = vT + (long)bz * D * S;
#pragma unroll
    for (int i = 0; i < 4; ++i)
      dst[(long)(d0 + ty + i * 8) * S + t0 + tx] = (bf16)tile[tx][ty + i * 8];
  }
}

// ---------------------------------------------------------------------------
// Shared machinery macros for the 32x32 split GEMM (R5/R13-verified).
#define STGM(slot, arr, base, koff, rr) \
  stage16((base) + (koff) + (long)(rr) * 131072, \
          lds + ((slot) * 4 + (arr)) * ARR + (rr) * 4096 + dstoff)

#define CLUSTERM(AF, BF) \
  __builtin_amdgcn_s_setprio(1); \
  _Pragma("unroll") \
  for (int s = 0; s < 2; ++s) \
    _Pragma("unroll") \
    for (int i = 0; i < 4; ++i) \
      _Pragma("unroll") \
      for (int j = 0; j < 2; ++j) \
        acc[i][j] = __builtin_amdgcn_mfma_f32_32x32x16_bf16(AF[i][s], BF[j][s], acc[i][j], 0, 0, 0); \
  __builtin_amdgcn_s_setprio(0)

// K-loop body shared textually between the two split kernels (verbatim R13).
#define SPLIT_KLOOP \
  STGM(0, 0, A_h + asrc, 0, 0); STGM(0, 0, A_h + asrc, 0, 1); \
  STGM(0, 2, B_h + bsrc, 0, 0); STGM(0, 2, B_h + bsrc, 0, 1); \
  STGM(0, 3, B_l + bsrc, 0, 0); STGM(0, 3, B_l + bsrc, 0, 1); \
  STGM(0, 1, A_l + asrc, 0, 0); STGM(0, 1, A_l + asrc, 0, 1); \
  VMCNT(4); \
  SBARRIER; \
  for (int t = 0; t < NTK; ++t) { \
    const int cur = t & 1, nxt = cur ^ 1; \
    const long kn = (long)(t + 1) * GBK; \
    const bool pf = (t + 1 < NTK); \
    const bf16* lA_h = lds + (cur * 4 + 0) * ARR; \
    const bf16* lA_l = lds + (cur * 4 + 1) * ARR; \
    const bf16* lB_h = lds + (cur * 4 + 2) * ARR; \
    const bf16* lB_l = lds + (cur * 4 + 3) * ARR; \
    _Pragma("unroll") \
    for (int i = 0; i < 4; ++i) \
      _Pragma("unroll") \
      for (int s = 0; s < 2; ++s) ah[i][s] = *(const bf16x8*)&lA_h[aoff[i][s]]; \
    _Pragma("unroll") \
    for (int j = 0; j < 2; ++j) \
      _Pragma("unroll") \
      for (int s = 0; s < 2; ++s) bh[j][s] = *(const bf16x8*)&lB_h[boff[j][s]]; \
    if (pf) { \
      STGM(nxt, 0, A_h + asrc, kn, 0); STGM(nxt, 0, A_h + asrc, kn, 1); \
      STGM(nxt, 2, B_h + bsrc, kn, 0); STGM(nxt, 2, B_h + bsrc, kn, 1); \
      VMCNT(6); \
    } else { VMCNT(2); } \
    SBARRIER; LGKM(0); SB0; \
    CLUSTERM(ah, bh); \
    SBARRIER; \
    _Pragma("unroll") \
    for (int j = 0; j < 2; ++j) \
      _Pragma("unroll") \
      for (int s = 0; s < 2; ++s) bl[j][s] = *(const bf16x8*)&lB_l[boff[j][s]]; \
    if (pf) { \
      STGM(nxt, 3, B_l + bsrc, kn, 0); STGM(nxt, 3, B_l + bsrc, kn, 1); \
      VMCNT(6); \
    } else { VMCNT(0); } \
    SBARRIER; LGKM(0); SB0; \
    CLUSTERM(ah, bl); \
    SBARRIER; \
    _Pragma("unroll") \
    for (int i = 0; i < 4; ++i) \
      _Pragma("unroll") \
      for (int s = 0; s < 2; ++s) al[i][s] = *(const bf16x8*)&lA_l[aoff[i][s]]; \
    if (pf) { \
      STGM(nxt, 1, A_l + asrc, kn, 0); STGM(nxt, 1, A_l + asrc, kn, 1); \
      VMCNT(4); \
    } \
    SBARRIER; LGKM(0); SB0; \
    CLUSTERM(al, bh); \
    SBARRIER; \
  }

#define SPLIT_PREAMBLE \
  const int tid = threadIdx.x; \
  const int lane = tid & 63, wid = tid >> 6; \
  const int wr = wid >> 2, wc = wid & 3; \
  const int lr = lane & 31; \
  const int lk = lane >> 5; \
  const int srow = tid >> 2; \
  const int csw = ((tid & 3) ^ ((srow >> 1) & 3)) * 8; \
  const int dstoff = wid * 512; \
  int aoff[4][2], boff[2][2]; \
  _Pragma("unroll") \
  for (int i = 0; i < 4; ++i) { \
    const int r = wr * 128 + i * 32 + lr; \
    _Pragma("unroll") \
    for (int s = 0; s < 2; ++s) \
      aoff[i][s] = r * 32 + (((2 * s + lk) ^ ((r >> 1) & 3)) * 8); \
  } \
  _Pragma("unroll") \
  for (int j = 0; j < 2; ++j) { \
    const int r = wc * 64 + j * 32 + lr; \
    _Pragma("unroll") \
    for (int s = 0; s < 2; ++s) \
      boff[j][s] = r * 32 + (((2 * s + lk) ^ ((r >> 1) & 3)) * 8); \
  } \
  f32x16 acc[4][2] = {}; \
  bf16x8 ah[4][2], al[4][2], bh[2][2], bl[2][2];

// ---------------------------------------------------------------------------
// BOTH projections in one grid-512 dispatch. op = swizzled-id >> 8 selects
// {query,Wq,bq,q-out} vs {key,Wk,bk,k-out}.
__global__ __launch_bounds__(512, 2) void gemm32_proj2(
    const bf16* __restrict__ qh, const bf16* __restrict__ ql,
    const bf16* __restrict__ kh, const bf16* __restrict__ kl,
    const bf16* __restrict__ Wqh, const bf16* __restrict__ Wql,
    const bf16* __restrict__ Wkh, const bf16* __restrict__ Wkl,
    const float* __restrict__ bq, const float* __restrict__ bk,
    bf16* __restrict__ qoh, bf16* __restrict__ qol,
    bf16* __restrict__ koh, bf16* __restrict__ kol) {
  __shared__ bf16 lds[2 * 4 * ARR];   // 128 KB

  SPLIT_PREAMBLE

  // bijective swizzle over 512 blocks (512 % 8 == 0)
  const int w = blockIdx.x;
  const int swz = (w & 7) * 64 + (w >> 3);
  const int op = swz >> 8;            // 0 = q-proj, 1 = k-proj
  const int rem = swz & 255;
  const int by = rem >> 2, bx = rem & 3;
  const long brow = (long)by * GBM, bcol = (long)bx * GBN;

  const bf16* A_h = op ? kh : qh;
  const bf16* A_l = op ? kl : ql;
  const bf16* B_h = op ? Wkh : Wqh;
  const bf16* B_l = op ? Wkl : Wql;
  const float* bias = op ? bk : bq;
  bf16* Ch = op ? koh : qoh;
  bf16* Cl = op ? kol : qol;

  const long asrc = (brow + srow) * 1024 + csw;
  const long bsrc = (bcol + srow) * 1024 + csw;

  SPLIT_KLOOP

  // Epilogue: split-bf16 out + col bias. 32x32 C/D frag [m74/m101]:
  // col = lane&31, row = (reg&3) + 8*(reg>>2) + 4*(lane>>5)
#pragma unroll
  for (int j = 0; j < 2; ++j) {
    const long col = bcol + wc * 64 + j * 32 + lr;
    const float bv = bias[col];
#pragma unroll
    for (int i = 0; i < 4; ++i) {
      const long row0 = brow + wr * 128 + i * 32 + 4 * lk;
#pragma unroll
      for (int r = 0; r < 16; ++r) {
        const long row = row0 + (r & 3) + 8 * (r >> 2);
        const float c = acc[i][j][r] + bv;
        const bf16 h = (bf16)c;
        const bf16 l = (bf16)(c - (float)h);
        const long idx = row * 1024 + col;
        Ch[idx] = h;
        Cl[idx] = l;
      }
    }
  }
}

// ---------------------------------------------------------------------------
// Energy split GEMM: fp32 out + attn_bias, batched z.
__global__ __launch_bounds__(512, 2) void gemm32_energy(
    const bf16* __restrict__ Ah_g, const bf16* __restrict__ Al_g, long a_bs,
    const bf16* __restrict__ Bh_g, const bf16* __restrict__ Bl_g, long b_bs,
    const float* __restrict__ bias,
    float* __restrict__ Cf, long c_bs) {
  __shared__ bf16 lds[2 * 4 * ARR];   // 128 KB

  SPLIT_PREAMBLE

  const int w = blockIdx.x;
  const int swz = (w & 7) * 32 + (w >> 3);
  const int z = swz >> 4, by = (swz >> 2) & 3, bx = swz & 3;
  const long brow = (long)by * GBM, bcol = (long)bx * GBN;

  const bf16* A_h = Ah_g + (long)z * a_bs;
  const bf16* A_l = Al_g + (long)z * a_bs;
  const bf16* B_h = Bh_g + (long)z * b_bs;
  const bf16* B_l = Bl_g + (long)z * b_bs;

  const long asrc = (brow + srow) * 1024 + csw;
  const long bsrc = (bcol + srow) * 1024 + csw;

  SPLIT_KLOOP

  float* Cz = Cf + (long)z * c_bs;
#pragma unroll
  for (int j = 0; j < 2; ++j) {
    const long col = bcol + wc * 64 + j * 32 + lr;
#pragma unroll
    for (int i = 0; i < 4; ++i) {
      const long row0 = brow + wr * 128 + i * 32 + 4 * lk;
#pragma unroll
      for (int r = 0; r < 16; ++r) {
        const long row = row0 + (r & 3) + 8 * (r >> 2);
        Cz[row * 1024 + col] = acc[i][j][r] + bias[row * 1024 + col];
      }
    }
  }
}

// ---------------------------------------------------------------------------
// Plain bf16 GEMM (PV) on 32x32 MFMA. 1 phase/K-tile, counted vmcnt(4);
// LDS 2 bufs x {A,B} = 64 KB.
__global__ __launch_bounds__(512, 2) void gemm32_plain(
    const bf16* __restrict__ A_g, long a_bs,
    const bf16* __restrict__ B_g, long b_bs,
    float* __restrict__ C, long c_bs) {
  __shared__ bf16 lds[2 * 2 * ARR];   // 64 KB

  const int tid = threadIdx.x;
  const int lane = tid & 63, wid = tid >> 6;
  const int wr = wid >> 2, wc = wid & 3;
  const int lr = lane & 31;
  const int lk = lane >> 5;

  const int w = blockIdx.x;
  const int swz = (w & 7) * 32 + (w >> 3);
  const int z = swz >> 4, by = (swz >> 2) & 3, bx = swz & 3;
  const long brow = (long)by * GBM, bcol = (long)bx * GBN;

  const bf16* A = A_g + (long)z * a_bs;
  const bf16* B = B_g + (long)z * b_bs;

  const int srow = tid >> 2;
  const int csw = ((tid & 3) ^ ((srow >> 1) & 3)) * 8;
  const long asrc = (brow + srow) * 1024 + csw;
  const long bsrc = (bcol + srow) * 1024 + csw;
  const int dstoff = wid * 512;

  int aoff[4][2], boff[2][2];
#pragma unroll
  for (int i = 0; i < 4; ++i) {
    const int r = wr * 128 + i * 32 + lr;
#pragma unroll
    for (int s = 0; s < 2; ++s)
      aoff[i][s] = r * 32 + (((2 * s + lk) ^ ((r >> 1) & 3)) * 8);
  }
#pragma unroll
  for (int j = 0; j < 2; ++j) {
    const int r = wc * 64 + j * 32 + lr;
#pragma unroll
    for (int s = 0; s < 2; ++s)
      boff[j][s] = r * 32 + (((2 * s + lk) ^ ((r >> 1) & 3)) * 8);
  }

  f32x16 acc[4][2] = {};
  bf16x8 af[4][2], bf_[2][2];

#define STG2(slot, arr, base, koff, rr) \
  stage16((base) + (koff) + (long)(rr) * 131072, \
          lds + ((slot) * 2 + (arr)) * ARR + (rr) * 4096 + dstoff)

  STG2(0, 0, A + asrc, 0, 0); STG2(0, 0, A + asrc, 0, 1);
  STG2(0, 1, B + bsrc, 0, 0); STG2(0, 1, B + bsrc, 0, 1);

  for (int t = 0; t < NTK; ++t) {
    const int cur = t & 1, nxt = cur ^ 1;
    const bf16* lA = lds + (cur * 2 + 0) * ARR;
    const bf16* lB = lds + (cur * 2 + 1) * ARR;

    if (t + 1 < NTK) {
      const long kn = (long)(t + 1) * GBK;
      STG2(nxt, 0, A + asrc, kn, 0); STG2(nxt, 0, A + asrc, kn, 1);
      STG2(nxt, 1, B + bsrc, kn, 0); STG2(nxt, 1, B + bsrc, kn, 1);
      VMCNT(4);
    } else {
      VMCNT(0);
    }
    SB0;
    SBARRIER;

#pragma unroll
    for (int i = 0; i < 4; ++i)
#pragma unroll
      for (int s = 0; s < 2; ++s) af[i][s] = *(const bf16x8*)&lA[aoff[i][s]];
#pragma unroll
    for (int j = 0; j < 2; ++j)
#pragma unroll
      for (int s = 0; s < 2; ++s) bf_[j][s] = *(const bf16x8*)&lB[boff[j][s]];
    LGKM(0); SB0;
    __builtin_amdgcn_s_setprio(1);
#pragma unroll
    for (int s = 0; s < 2; ++s)
#pragma unroll
      for (int i = 0; i < 4; ++i)
#pragma unroll
        for (int j = 0; j < 2; ++j)
          acc[i][j] = __builtin_amdgcn_mfma_f32_32x32x16_bf16(af[i][s], bf_[j][s], acc[i][j], 0, 0, 0);
    __builtin_amdgcn_s_setprio(0);

    SBARRIER;
  }
#undef STG2

  float* Cz = C + (long)z * c_bs;
#pragma unroll
  for (int j = 0; j < 2; ++j) {
    const long col = bcol + wc * 64 + j * 32 + lr;
#pragma unroll
    for (int i = 0; i < 4; ++i) {
      const long row0 = brow + wr * 128 + i * 32 + 4 * lk;
#pragma unroll
      for (int r = 0; r < 16; ++r) {
        const long row = row0 + (r & 3) + 8 * (r >> 2);
        Cz[row * 1024 + col] = acc[i][j][r];
      }
    }
  }
}

// ---------------------------------------------------------------------------
__global__ __launch_bounds__(256) void softmax_rows(
    float* __restrict__ attn, bf16* __restrict__ attn_bf) {
  const long row = blockIdx.x;
  float* p = attn + row * 1024;
  const int tid = threadIdx.x, lane = tid & 63, wid = tid >> 6;

  f32x4 x = ((const f32x4*)p)[tid];
  float m = fmaxf(fmaxf(x[0], x[1]), fmaxf(x[2], x[3]));
#pragma unroll
  for (int off = 32; off; off >>= 1) m = fmaxf(m, __shfl_xor(m, off));
  __shared__ float redm[4];
  if (lane == 0) redm[wid] = m;
  __syncthreads();
  m = fmaxf(fmaxf(redm[0], redm[1]), fmaxf(redm[2], redm[3]));

  f32x4 e;
#pragma unroll
  for (int j = 0; j < 4; ++j) e[j] = __expf(x[j] - m);
  float s = e[0] + e[1] + e[2] + e[3];
#pragma unroll
  for (int off = 32; off; off >>= 1) s += __shfl_xor(s, off);
  __shared__ float reds[4];
  if (lane == 0) reds[wid] = s;
  __syncthreads();
  s = reds[0] + reds[1] + reds[2] + reds[3];

  const float inv = 1.0f / s;
  f32x4 r;
  bf16x4 rb;
#pragma unroll
  for (int j = 0; j < 4; ++j) {
    r[j] = e[j] * inv;
    rb[j] = (bf16)r[j];
  }
  ((f32x4*)p)[tid] = r;
  ((bf16x4*)(attn_bf + row * 1024))[tid] = rb;
}

// ---------------------------------------------------------------------------
extern "C" void kernel_launch(void* const* d_in, const int* in_sizes, int n_in,
                              void* d_out, int out_size, void* d_ws, size_t ws_size,
                              hipStream_t stream) {
  const float* query     = (const float*)d_in[0];
  const float* key       = (const float*)d_in[1];
  const float* value     = (const float*)d_in[2];
  const float* attn_bias = (const float*)d_in[3];
  const float* Wq        = (const float*)d_in[4];
  const float* bq        = (const float*)d_in[5];
  const float* Wk        = (const float*)d_in[6];
  const float* bk        = (const float*)d_in[7];

  float* out  = (float*)d_out;          // [16,1024,1024]
  float* attn = out + NBSD;             // [16,1024,1024]

  // ws carve (bf16 elements): projected splits + W splits + valueT + attn_bf
  // = 6*NBSD + 4*D*D = 200 MiB (no aliasing).
  bf16* ws    = (bf16*)d_ws;
  bf16* q_hi  = ws;                     // projected q splits
  bf16* q_lo  = ws + NBSD;
  bf16* k_hi  = ws + 2 * NBSD;          // projected k splits
  bf16* k_lo  = ws + 3 * NBSD;
  bf16* Wq_hi = ws + 4 * NBSD;
  bf16* Wq_lo = Wq_hi + (long)D * D;
  bf16* Wk_hi = Wq_lo + (long)D * D;
  bf16* Wk_lo = Wk_hi + (long)D * D;
  bf16* valueT  = Wk_lo + (long)D * D;  // dedicated (no aliasing)
  bf16* attn_bf = valueT + NBSD;
  // INPUT splits live in d_out (dead before their regions are written):
  //   query splits in `out` (PV writes out last);
  //   key splits in `attn` (energy writes attn after proj2 consumed them).
  bf16* query_hi = (bf16*)out;
  bf16* query_lo = query_hi + NBSD;
  bf16* key_hi   = (bf16*)attn;
  bf16* key_lo   = key_hi + NBSD;

  // 1) all split conversions + value transpose in ONE dispatch
  fused_converts_t<<<21504, 256, 0, stream>>>(query, key, Wq, Wk, value,
                                              query_hi, query_lo, key_hi, key_lo,
                                              Wq_hi, Wq_lo, Wk_hi, Wk_lo,
                                              valueT);

  // 2) BOTH projections in ONE grid-512 dispatch
  gemm32_proj2<<<512, 512, 0, stream>>>(query_hi, query_lo, key_hi, key_lo,
                                        Wq_hi, Wq_lo, Wk_hi, Wk_lo,
                                        bq, bk,
                                        q_hi, q_lo, k_hi, k_lo);

  // 3) energy = q k^T + bias (key input splits in attn now dead)
  gemm32_energy<<<256, 512, 0, stream>>>(q_hi, q_lo, (long)S * D, k_hi, k_lo, (long)S * D,
                                         attn_bias, attn, (long)S * S);

  // 4) softmax in place + bf16 copy
  softmax_rows<<<BATCH * S, 256, 0, stream>>>(attn, attn_bf);

  // 5) out = attention @ value (query input splits in out now dead)
  gemm32_plain<<<256, 512, 0, stream>>>(attn_bf, (long)S * S, valueT, (long)D * S,
                                        out, (long)S * D);
}